// Round 1
// baseline (2159.656 us; speedup 1.0000x reference)
//
#include <hip/hip_runtime.h>
#include <math.h>

typedef unsigned short u16;
typedef unsigned int   u32;
typedef float f32x4 __attribute__((ext_vector_type(4)));
typedef __bf16 bf16x8 __attribute__((ext_vector_type(8)));

#define T_LEN  1024
#define DMODEL 1024
#define NTOK   2048   // B*T
#define NHEAD  16
#define HDIM   64
#define NEXP   8
#define FFDIM  4096
#define NSLOT  4096   // NTOK * topk

__device__ __forceinline__ u16 f2bf(float f) {          // RNE, matches HW cvt
  union { float f; u32 u; } v; v.f = f;
  u32 r = v.u + 0x7FFFu + ((v.u >> 16) & 1u);
  return (u16)(r >> 16);
}
__device__ __forceinline__ float bf2f(u16 h) {
  union { u32 u; float f; } v; v.u = ((u32)h) << 16; return v.f;
}

// ---------------- RMSNorm (f64 accumulate; writes f32, optionally bf16) ----
template<int WRITE_B>
__global__ __launch_bounds__(256) void tb_rms(const float* __restrict__ x,
    const float* __restrict__ scale, float* __restrict__ out_f, u16* __restrict__ out_b) {
  int t = blockIdx.x, tid = threadIdx.x;
  const float* xr = x + (size_t)t * DMODEL;
  float4 v = *(const float4*)(xr + tid * 4);
  double ss = (double)v.x*v.x + (double)v.y*v.y + (double)v.z*v.z + (double)v.w*v.w;
  #pragma unroll
  for (int off = 32; off; off >>= 1) ss += __shfl_xor(ss, off);
  __shared__ double red[4];
  if ((tid & 63) == 0) red[tid >> 6] = ss;
  __syncthreads();
  double denom = sqrt((red[0]+red[1]+red[2]+red[3]) / (double)DMODEL) + 1e-5;
  float4 sc = *(const float4*)(scale + tid * 4);
  float y0 = (float)((double)v.x / denom * (double)sc.x);
  float y1 = (float)((double)v.y / denom * (double)sc.y);
  float y2 = (float)((double)v.z / denom * (double)sc.z);
  float y3 = (float)((double)v.w / denom * (double)sc.w);
  *(float4*)(out_f + (size_t)t*DMODEL + tid*4) = make_float4(y0,y1,y2,y3);
  if (WRITE_B) {
    u16* ob = out_b + (size_t)t*DMODEL + tid*4;
    ob[0]=f2bf(y0); ob[1]=f2bf(y1); ob[2]=f2bf(y2); ob[3]=f2bf(y3);
  }
}

// ---------------- fp32 GEMM, 128x128 tile, BK=16, 512 thr (attention path) -
template<int RESID>
__global__ __launch_bounds__(512) void tb_gemm_f32(const float* __restrict__ A,
    const float* __restrict__ Bm, const float* __restrict__ bias,
    const float* __restrict__ resid, float* __restrict__ C, int M, int N, int K) {
  __shared__ __align__(16) float As[16][132];   // [k][m] transposed
  __shared__ __align__(16) float Bs[16][136];   // [k][n]
  int tid = threadIdx.x;
  int row0 = blockIdx.y * 128, col0 = blockIdx.x * 128;
  int ty = tid >> 5, tx = tid & 31;             // 16 x 32 threads, micro 8x4
  float acc[8][4];
  #pragma unroll
  for (int i=0;i<8;++i){ acc[i][0]=0.f;acc[i][1]=0.f;acc[i][2]=0.f;acc[i][3]=0.f; }
  for (int k0 = 0; k0 < K; k0 += 16) {
    { int r = tid >> 2, kk = (tid & 3) * 4;
      float4 va = *(const float4*)(A + (size_t)(row0 + r) * K + k0 + kk);
      As[kk+0][r]=va.x; As[kk+1][r]=va.y; As[kk+2][r]=va.z; As[kk+3][r]=va.w;
      int kb = tid >> 5, n4 = (tid & 31) * 4;
      float4 vb = *(const float4*)(Bm + (size_t)(k0 + kb) * N + col0 + n4);
      *(float4*)&Bs[kb][n4] = vb; }
    __syncthreads();
    #pragma unroll
    for (int kk = 0; kk < 16; ++kk) {
      float a[8], b[4];
      *(float4*)&a[0] = *(const float4*)&As[kk][ty*8];
      *(float4*)&a[4] = *(const float4*)&As[kk][ty*8+4];
      *(float4*)&b[0] = *(const float4*)&Bs[kk][tx*4];
      #pragma unroll
      for (int i=0;i<8;++i)
        #pragma unroll
        for (int j=0;j<4;++j) acc[i][j] = fmaf(a[i], b[j], acc[i][j]);
    }
    __syncthreads();
  }
  #pragma unroll
  for (int i = 0; i < 8; ++i) {
    int r = row0 + ty*8 + i, c = col0 + tx*4;
    float4 o;
    o.x = acc[i][0] + bias[c+0]; o.y = acc[i][1] + bias[c+1];
    o.z = acc[i][2] + bias[c+2]; o.w = acc[i][3] + bias[c+3];
    if (RESID) { const float4 rv = *(const float4*)(resid + (size_t)r*N + c);
      o.x += rv.x; o.y += rv.y; o.z += rv.z; o.w += rv.w; }
    *(float4*)(C + (size_t)r*N + c) = o;
  }
}

// ---------------- RoPE trig table (f64 -> f32; matches np f64 reference) ---
__global__ void tb_trig(float* __restrict__ tab) {
  int t = blockIdx.x, d = threadIdx.x;   // d in [0,32)
  double theta = pow(10000.0, -(double)d / 32.0);
  double ang = (double)t * theta;
  tab[(t*32 + d)*2 + 0] = (float)cos(ang);
  tab[(t*32 + d)*2 + 1] = (float)sin(ang);
}

// ---------------- qkv (N,3D) -> rope(q),rope(k),v in (B,H,T,HD) ------------
__global__ __launch_bounds__(256) void tb_rope(const float* __restrict__ qkv,
    const float* __restrict__ tab, float* __restrict__ Q, float* __restrict__ K,
    float* __restrict__ V) {
  int n = blockIdx.x;                 // b*T + t
  int b = n >> 10, t = n & 1023;
  const float* src = qkv + (size_t)n * 3072;
  for (int idx = threadIdx.x; idx < 512; idx += 256) {
    int h = idx >> 5, d = idx & 31;
    float ca = tab[(t*32+d)*2], sa = tab[(t*32+d)*2+1];
    size_t dst = ((size_t)(b*NHEAD + h) * T_LEN + t) * HDIM;
    { float x1 = src[h*64 + d], x2 = src[h*64 + d + 32];
      Q[dst + d]      = x1*ca - x2*sa;
      Q[dst + d + 32] = x1*sa + x2*ca; }
    { float x1 = src[1024 + h*64 + d], x2 = src[1024 + h*64 + d + 32];
      K[dst + d]      = x1*ca - x2*sa;
      K[dst + d + 32] = x1*sa + x2*ca; }
  }
  for (int c = threadIdx.x; c < 1024; c += 256) {
    int h = c >> 6, d = c & 63;
    V[((size_t)(b*NHEAD + h) * T_LEN + t) * HDIM + d] = src[2048 + c];
  }
}

// ---------------- causal flash attention, fp32, 16 q/block (4 waves x 4q) --
__global__ __launch_bounds__(256) void tb_attn(const float* __restrict__ Qg,
    const float* __restrict__ Kg, const float* __restrict__ Vg, float* __restrict__ Og) {
  __shared__ float Ks[64][65];
  __shared__ float Vs[64][65];
  int bh = blockIdx.x >> 6;
  int q0 = (blockIdx.x & 63) << 4;
  int lane = threadIdx.x & 63, wave = threadIdx.x >> 6;
  int b = bh >> 4, h = bh & 15;
  const float* Qb = Qg + (size_t)bh * (T_LEN*HDIM);
  const float* Kb = Kg + (size_t)bh * (T_LEN*HDIM);
  const float* Vb = Vg + (size_t)bh * (T_LEN*HDIM);
  int wq = q0 + wave * 4;
  float qreg[4], mrun[4], lrun[4], oacc[4];
  #pragma unroll
  for (int qi = 0; qi < 4; ++qi) {
    qreg[qi] = Qb[(size_t)(wq + qi) * HDIM + lane];
    mrun[qi] = -1e30f; lrun[qi] = 0.f; oacc[qi] = 0.f;
  }
  int ntile = ((q0 + 15) >> 6) + 1;
  for (int kt = 0; kt < ntile; ++kt) {
    int k0 = kt * 64;
    __syncthreads();
    #pragma unroll
    for (int p = 0; p < 4; ++p) {
      int r = (threadIdx.x >> 4) + p * 16, c4 = (threadIdx.x & 15) * 4;
      float4 kv = *(const float4*)(Kb + (size_t)(k0 + r) * HDIM + c4);
      Ks[r][c4+0]=kv.x; Ks[r][c4+1]=kv.y; Ks[r][c4+2]=kv.z; Ks[r][c4+3]=kv.w;
      float4 vv = *(const float4*)(Vb + (size_t)(k0 + r) * HDIM + c4);
      Vs[r][c4+0]=vv.x; Vs[r][c4+1]=vv.y; Vs[r][c4+2]=vv.z; Vs[r][c4+3]=vv.w;
    }
    __syncthreads();
    for (int qi = 0; qi < 4; ++qi) {
      int qg = wq + qi;
      if (k0 > qg) continue;
      float s = 0.f;
      #pragma unroll
      for (int d = 0; d < 64; ++d) s = fmaf(__shfl(qreg[qi], d), Ks[lane][d], s);
      int kg = k0 + lane;
      bool valid = (kg <= qg);
      s = valid ? s * 0.125f : -1e30f;
      float mx = s;
      #pragma unroll
      for (int off = 32; off; off >>= 1) mx = fmaxf(mx, __shfl_xor(mx, off));
      float mnew = fmaxf(mrun[qi], mx);
      float alpha = expf(mrun[qi] - mnew);
      float p = valid ? expf(s - mnew) : 0.f;
      float ps = p;
      #pragma unroll
      for (int off = 32; off; off >>= 1) ps += __shfl_xor(ps, off);
      lrun[qi] = lrun[qi] * alpha + ps;
      float ov = oacc[qi] * alpha;
      #pragma unroll
      for (int kk = 0; kk < 64; ++kk) ov = fmaf(__shfl(p, kk), Vs[kk][lane], ov);
      oacc[qi] = ov; mrun[qi] = mnew;
    }
  }
  #pragma unroll
  for (int qi = 0; qi < 4; ++qi) {
    int q = wq + qi;
    Og[((size_t)b * T_LEN + q) * DMODEL + h * HDIM + lane] = oacc[qi] / lrun[qi];
  }
}

// ---------------- router: f64 logits, top-2, gate softmax, counts ----------
__global__ __launch_bounds__(64) void tb_gating(const float* __restrict__ xn2,
    const float* __restrict__ wg, const float* __restrict__ bg,
    int* __restrict__ top_idx, float* __restrict__ gate_w, int* __restrict__ counts) {
  int t = blockIdx.x, lane = threadIdx.x;
  const float* xr = xn2 + (size_t)t * DMODEL;
  double part[8];
  #pragma unroll
  for (int e = 0; e < 8; ++e) part[e] = 0.0;
  for (int i = lane; i < DMODEL; i += 64) {
    double xv = (double)xr[i];
    const float* wr = wg + (size_t)i * 8;
    #pragma unroll
    for (int e = 0; e < 8; ++e) part[e] += xv * (double)wr[e];
  }
  #pragma unroll
  for (int e = 0; e < 8; ++e)
    for (int off = 32; off; off >>= 1) part[e] += __shfl_xor(part[e], off);
  if (lane == 0) {
    double lg[8];
    for (int e = 0; e < 8; ++e) lg[e] = part[e] + (double)bg[e];
    int i1 = 0;
    for (int e = 1; e < 8; ++e) if (lg[e] > lg[i1]) i1 = e;
    int i2 = (i1 == 0) ? 1 : 0;
    for (int e = 0; e < 8; ++e) if (e != i1 && lg[e] > lg[i2]) i2 = e;
    double e2 = exp(lg[i2] - lg[i1]);
    double den = 1.0 + e2;
    top_idx[t*2] = i1; top_idx[t*2+1] = i2;
    gate_w[t*2] = (float)(1.0/den); gate_w[t*2+1] = (float)(e2/den);
    atomicAdd(&counts[i1], 1); atomicAdd(&counts[i2], 1);
  }
}

__global__ void tb_scan(const int* __restrict__ counts, int* __restrict__ offs,
    int* __restrict__ cursor, float* __restrict__ aux_out) {
  if (threadIdx.x == 0) {
    int off = 0; float aux = 0.f;
    for (int e = 0; e < 8; ++e) {
      offs[e] = off; cursor[e] = off; off += counts[e];
      float fr = (float)counts[e] / 4096.0f - 0.125f;
      aux += fr * fr;
    }
    aux_out[0] = aux;
  }
}

// ---------------- gather token rows into expert-grouped Xg (bf16) ----------
__global__ __launch_bounds__(128) void tb_gather(const u16* __restrict__ xn2b,
    const int* __restrict__ top_idx, int* __restrict__ cursor,
    int* __restrict__ slot_of, u16* __restrict__ Xg) {
  int t = blockIdx.x;
  __shared__ int sl[2];
  if (threadIdx.x < 2) {
    int e = top_idx[t*2 + threadIdx.x];
    int s = atomicAdd(&cursor[e], 1);
    sl[threadIdx.x] = s;
    slot_of[t*2 + threadIdx.x] = s;
  }
  __syncthreads();
  uint4 v = *(const uint4*)(xn2b + (size_t)t * DMODEL + threadIdx.x * 8);
  *(uint4*)(Xg + (size_t)sl[0] * DMODEL + threadIdx.x * 8) = v;
  *(uint4*)(Xg + (size_t)sl[1] * DMODEL + threadIdx.x * 8) = v;
}

// ---------------- grouped MoE GEMM, bf16 MFMA 16x16x32, 128x128 tile -------
// MODE 0: silu(acc+bias) -> bf16 ; MODE 1: (acc+bias)*Hprev -> bf16 (inplace);
// MODE 2: acc+bias -> f32
template<int MODE>
__global__ __launch_bounds__(256) void tb_moe_gemm(const u16* __restrict__ Ag,
    const float* __restrict__ Wf, const float* __restrict__ bias_b,
    const u16* __restrict__ Hprev, u16* __restrict__ out_b, float* __restrict__ out_f,
    const int* __restrict__ counts, const int* __restrict__ offs, int K, int N) {
  int e = blockIdx.z;
  int cnt = counts[e];
  if ((int)blockIdx.y * 128 >= cnt) return;
  int row0 = offs[e] + blockIdx.y * 128;
  int rend = offs[e] + cnt;
  int col0 = blockIdx.x * 128;
  const float* Bw = Wf + (size_t)e * K * N;
  const float* bias = bias_b + (size_t)e * N;
  __shared__ __align__(16) u16 As[128*40];   // [row][k], stride 40 bf16
  __shared__ __align__(16) u16 Bs[128*40];   // [col][k] (transposed)
  int tid = threadIdx.x;
  int lane = tid & 63, wave = tid >> 6;
  int wm = wave >> 1, wn = wave & 1;
  int l15 = lane & 15, l4 = lane >> 4;
  f32x4 zero = {0.f, 0.f, 0.f, 0.f};
  f32x4 acc[4][4];
  #pragma unroll
  for (int i=0;i<4;++i) for (int j=0;j<4;++j) acc[i][j] = zero;
  for (int k0 = 0; k0 < K; k0 += 32) {
    #pragma unroll
    for (int p = 0; p < 2; ++p) {             // A: 128 rows x 32 bf16
      int r = (tid >> 2) + p * 64, kk = (tid & 3) * 8;
      uint4 v = make_uint4(0,0,0,0);
      if (row0 + r < rend) v = *(const uint4*)(Ag + (size_t)(row0 + r) * K + k0 + kk);
      *(uint4*)(As + r*40 + kk) = v;
    }
    #pragma unroll
    for (int p = 0; p < 4; ++p) {             // B: 32 k x 128 n fp32 -> bf16 T
      int kk = (tid >> 5) + p * 8, n4 = (tid & 31) * 4;
      float4 v = *(const float4*)(Bw + (size_t)(k0 + kk) * N + col0 + n4);
      Bs[(n4+0)*40 + kk] = f2bf(v.x);
      Bs[(n4+1)*40 + kk] = f2bf(v.y);
      Bs[(n4+2)*40 + kk] = f2bf(v.z);
      Bs[(n4+3)*40 + kk] = f2bf(v.w);
    }
    __syncthreads();
    bf16x8 af[4], bfr[4];
    #pragma unroll
    for (int mi = 0; mi < 4; ++mi)
      af[mi] = *(const bf16x8*)(As + (wm*64 + mi*16 + l15)*40 + l4*8);
    #pragma unroll
    for (int ni = 0; ni < 4; ++ni)
      bfr[ni] = *(const bf16x8*)(Bs + (wn*64 + ni*16 + l15)*40 + l4*8);
    #pragma unroll
    for (int mi = 0; mi < 4; ++mi)
      #pragma unroll
      for (int ni = 0; ni < 4; ++ni)
        acc[mi][ni] = __builtin_amdgcn_mfma_f32_16x16x32_bf16(af[mi], bfr[ni], acc[mi][ni], 0, 0, 0);
    __syncthreads();
  }
  #pragma unroll
  for (int mi = 0; mi < 4; ++mi) {
    #pragma unroll
    for (int r = 0; r < 4; ++r) {
      int row = row0 + wm*64 + mi*16 + l4*4 + r;
      if (row >= rend) continue;
      #pragma unroll
      for (int ni = 0; ni < 4; ++ni) {
        int col = col0 + wn*64 + ni*16 + l15;
        float vv = acc[mi][ni][r] + bias[col];
        size_t oi = (size_t)row * N + col;
        if (MODE == 0)      out_b[oi] = f2bf(vv / (1.f + expf(-vv)));
        else if (MODE == 1) out_b[oi] = f2bf(bf2f(Hprev[oi]) * vv);
        else                out_f[oi] = vv;
      }
    }
  }
}

// ---------------- final: out = x1 + g0*outp[s0] + g1*outp[s1] --------------
__global__ __launch_bounds__(256) void tb_combine(const float* __restrict__ x1,
    const float* __restrict__ outp, const int* __restrict__ slot_of,
    const float* __restrict__ gate_w, float* __restrict__ out) {
  int t = blockIdx.x;
  int s0 = slot_of[t*2], s1 = slot_of[t*2+1];
  float g0 = gate_w[t*2], g1 = gate_w[t*2+1];
  int c = threadIdx.x * 4;
  float4 a  = *(const float4*)(x1   + (size_t)t *DMODEL + c);
  float4 p0 = *(const float4*)(outp + (size_t)s0*DMODEL + c);
  float4 p1 = *(const float4*)(outp + (size_t)s1*DMODEL + c);
  float4 o;
  o.x = a.x + g0*p0.x + g1*p1.x;
  o.y = a.y + g0*p0.y + g1*p1.y;
  o.z = a.z + g0*p0.z + g1*p1.z;
  o.w = a.w + g0*p0.w + g1*p1.w;
  *(float4*)(out + (size_t)t*DMODEL + c) = o;
}

extern "C" void kernel_launch(void* const* d_in, const int* in_sizes, int n_in,
                              void* d_out, int out_size, void* d_ws, size_t ws_size,
                              hipStream_t stream) {
  const float* x      = (const float*)d_in[0];
  const float* w_qkv  = (const float*)d_in[1];
  const float* b_qkv  = (const float*)d_in[2];
  const float* w_out  = (const float*)d_in[3];
  const float* b_out  = (const float*)d_in[4];
  const float* scale1 = (const float*)d_in[5];
  const float* scale2 = (const float*)d_in[6];
  const float* w_gate = (const float*)d_in[7];
  const float* b_gate = (const float*)d_in[8];
  const float* w1     = (const float*)d_in[9];
  const float* b1     = (const float*)d_in[10];
  const float* w2     = (const float*)d_in[11];
  const float* b2     = (const float*)d_in[12];
  const float* wp     = (const float*)d_in[13];
  const float* bp     = (const float*)d_in[14];
  float* out = (float*)d_out;

  char* ws = (char*)d_ws;
  const size_t MB = 1024 * 1024;
  // Phase overlay: attention scratch [28MB,84MB) is reused by MoE scratch.
  float* XN1  = (float*)(ws + 0*MB);    // 8MB  rmsnorm1 (fp32)
  float* X1   = (float*)(ws + 8*MB);    // 8MB  x + attn_out
  float* XN2F = (float*)(ws + 16*MB);   // 8MB  rmsnorm2 fp32 (router input)
  u16*   XN2B = (u16*)  (ws + 24*MB);   // 4MB  rmsnorm2 bf16 (expert input)
  float* QKV  = (float*)(ws + 28*MB);   // 24MB
  u16*   XG   = (u16*)  (ws + 28*MB);   // 8MB  (reuse)
  u16*   HB   = (u16*)  (ws + 36*MB);   // 32MB (reuse)
  float* Qb   = (float*)(ws + 52*MB);   // 8MB
  float* Kb   = (float*)(ws + 60*MB);   // 8MB
  float* Vb   = (float*)(ws + 68*MB);   // 8MB
  float* OUTP = (float*)(ws + 68*MB);   // 16MB (reuse)
  float* Ob   = (float*)(ws + 76*MB);   // 8MB
  char*  GT   = ws + 84*MB;
  int*   top_idx = (int*)  (GT);
  float* gate_w  = (float*)(GT + 16*1024);
  int*   slot_of = (int*)  (GT + 32*1024);
  int*   counts  = (int*)  (GT + 48*1024);
  int*   offs    = (int*)  (GT + 48*1024 + 64);
  int*   cursor  = (int*)  (GT + 48*1024 + 128);
  float* trig    = (float*)(GT + 64*1024);   // 256KB cos/sin table

  hipMemsetAsync(counts, 0, 32, stream);
  tb_trig<<<1024, 32, 0, stream>>>(trig);
  tb_rms<0><<<2048, 256, 0, stream>>>(x, scale1, XN1, nullptr);
  tb_gemm_f32<0><<<dim3(24,16), 512, 0, stream>>>(XN1, w_qkv, b_qkv, nullptr, QKV, 2048, 3072, 1024);
  tb_rope<<<2048, 256, 0, stream>>>(QKV, trig, Qb, Kb, Vb);
  tb_attn<<<2048, 256, 0, stream>>>(Qb, Kb, Vb, Ob);
  tb_gemm_f32<1><<<dim3(8,16), 512, 0, stream>>>(Ob, w_out, b_out, x, X1, 2048, 1024, 1024);
  tb_rms<1><<<2048, 256, 0, stream>>>(X1, scale2, XN2F, XN2B);
  tb_gating<<<2048, 64, 0, stream>>>(XN2F, w_gate, b_gate, top_idx, gate_w, counts);
  tb_scan<<<1, 64, 0, stream>>>(counts, offs, cursor, out + (size_t)NTOK*DMODEL);
  tb_gather<<<2048, 128, 0, stream>>>(XN2B, top_idx, cursor, slot_of, XG);
  tb_moe_gemm<0><<<dim3(32,16,8), 256, 0, stream>>>(XG, w1, b1, nullptr, HB, nullptr, counts, offs, 1024, 4096);
  tb_moe_gemm<1><<<dim3(32,16,8), 256, 0, stream>>>(XG, w2, b2, HB, HB, nullptr, counts, offs, 1024, 4096);
  tb_moe_gemm<2><<<dim3(8,16,8), 256, 0, stream>>>(HB, wp, bp, nullptr, nullptr, OUTP, counts, offs, 4096, 1024);
  tb_combine<<<2048, 256, 0, stream>>>(X1, OUTP, slot_of, gate_w, out);
}

// Round 2
// 1180.468 us; speedup vs baseline: 1.8295x; 1.8295x over previous
//
#include <hip/hip_runtime.h>
#include <math.h>

typedef unsigned short u16;
typedef unsigned int   u32;
typedef float f32x4 __attribute__((ext_vector_type(4)));
typedef __bf16 bf16x8 __attribute__((ext_vector_type(8)));

#define T_LEN  1024
#define DMODEL 1024
#define NTOK   2048
#define NHEAD  16
#define HDIM   64
#define NEXP   8
#define FFDIM  4096

__device__ __forceinline__ u16 f2bf(float f) {          // RNE
  union { float f; u32 u; } v; v.f = f;
  u32 r = v.u + 0x7FFFu + ((v.u >> 16) & 1u);
  return (u16)(r >> 16);
}
__device__ __forceinline__ float bf2f(u16 h) {
  union { u32 u; float f; } v; v.u = ((u32)h) << 16; return v.f;
}
union b8u { uint4 u; bf16x8 b; };

// split 16 f32 -> 8 packed u32 hi + 8 packed u32 lo
__device__ __forceinline__ void split16(const float* src, u32* H, u32* L) {
  #pragma unroll
  for (int j = 0; j < 8; ++j) {
    float a = src[2*j], b = src[2*j+1];
    u16 ha = f2bf(a), hb = f2bf(b);
    u16 la = f2bf(a - bf2f(ha)), lb = f2bf(b - bf2f(hb));
    H[j] = (u32)ha | ((u32)hb << 16);
    L[j] = (u32)la | ((u32)lb << 16);
  }
}

// ---------------- RMSNorm (f64 accumulate) ---------------------------------
template<int WRITE_B>
__global__ __launch_bounds__(256) void tb_rms(const float* __restrict__ x,
    const float* __restrict__ scale, float* __restrict__ out_f, u16* __restrict__ out_b) {
  int t = blockIdx.x, tid = threadIdx.x;
  const float* xr = x + (size_t)t * DMODEL;
  float4 v = *(const float4*)(xr + tid * 4);
  double ss = (double)v.x*v.x + (double)v.y*v.y + (double)v.z*v.z + (double)v.w*v.w;
  #pragma unroll
  for (int off = 32; off; off >>= 1) ss += __shfl_xor(ss, off);
  __shared__ double red[4];
  if ((tid & 63) == 0) red[tid >> 6] = ss;
  __syncthreads();
  double denom = sqrt((red[0]+red[1]+red[2]+red[3]) / (double)DMODEL) + 1e-5;
  float4 sc = *(const float4*)(scale + tid * 4);
  float y0 = (float)((double)v.x / denom * (double)sc.x);
  float y1 = (float)((double)v.y / denom * (double)sc.y);
  float y2 = (float)((double)v.z / denom * (double)sc.z);
  float y3 = (float)((double)v.w / denom * (double)sc.w);
  *(float4*)(out_f + (size_t)t*DMODEL + tid*4) = make_float4(y0,y1,y2,y3);
  if (WRITE_B) {
    u16* ob = out_b + (size_t)t*DMODEL + tid*4;
    ob[0]=f2bf(y0); ob[1]=f2bf(y1); ob[2]=f2bf(y2); ob[3]=f2bf(y3);
  }
}

// ---------------- weight pre-split+transpose: W[k][n] f32 -> Wt[n][k] bf16 -
template<int HILO>
__global__ __launch_bounds__(256) void tb_wsplit(const float* __restrict__ W,
    u16* __restrict__ Wh, u16* __restrict__ Wl, int K, int N) {
  __shared__ float Tf[64*68];
  size_t eo = (size_t)blockIdx.z * (size_t)K * N;
  const float* Wb = W + eo;
  int n0 = blockIdx.x*64, k0 = blockIdx.y*64;
  int tid = threadIdx.x;
  int r = tid >> 2, c = tid & 3;
  const float* wp = Wb + (size_t)(k0+r)*N + n0 + c*16;
  float vv[16];
  *(float4*)&vv[0]  = ((const float4*)wp)[0];
  *(float4*)&vv[4]  = ((const float4*)wp)[1];
  *(float4*)&vv[8]  = ((const float4*)wp)[2];
  *(float4*)&vv[12] = ((const float4*)wp)[3];
  #pragma unroll
  for (int j = 0; j < 16; ++j) Tf[(c*16+j)*68 + r] = vv[j];
  __syncthreads();
  int n = tid >> 2, kc = tid & 3;
  float tv[16];
  #pragma unroll
  for (int j = 0; j < 16; ++j) tv[j] = Tf[n*68 + kc*16 + j];
  u32 H[8], L[8];
  split16(tv, H, L);
  u16* oh = Wh + eo + (size_t)(n0+n)*K + k0 + kc*16;
  *(uint4*)oh       = make_uint4(H[0],H[1],H[2],H[3]);
  *(uint4*)(oh + 8) = make_uint4(H[4],H[5],H[6],H[7]);
  if (HILO) {
    u16* ol = Wl + eo + (size_t)(n0+n)*K + k0 + kc*16;
    *(uint4*)ol       = make_uint4(L[0],L[1],L[2],L[3]);
    *(uint4*)(ol + 8) = make_uint4(L[4],L[5],L[6],L[7]);
  }
}

// ---------------- split-bf16 MFMA GEMM: C = A(f32) * Wt + bias [+resid] ----
template<int RESID>
__global__ __launch_bounds__(256) void tb_gemm_sp(const float* __restrict__ A,
    const u16* __restrict__ Bhg, const u16* __restrict__ Blg,
    const float* __restrict__ bias, const float* __restrict__ resid,
    float* __restrict__ C, int M, int N, int K) {
  __shared__ __align__(16) u16 Ah[128*40], Al[128*40], Bh[128*40], Bl[128*40];
  int tid = threadIdx.x;
  int row0 = blockIdx.y * 128, col0 = blockIdx.x * 128;
  int lane = tid & 63, wave = tid >> 6;
  int wm = wave >> 1, wn = wave & 1;
  int l15 = lane & 15, l4 = lane >> 4;
  int sr = tid >> 1, skh = (tid & 1) * 16;
  f32x4 zero = {0.f,0.f,0.f,0.f};
  f32x4 acc[4][4];
  #pragma unroll
  for (int i=0;i<4;++i) for (int j=0;j<4;++j) acc[i][j] = zero;
  for (int k0 = 0; k0 < K; k0 += 32) {
    { // A stage: f32 -> hi/lo bf16
      const float* ap = A + (size_t)(row0+sr)*K + k0 + skh;
      float vv[16];
      *(float4*)&vv[0]  = ((const float4*)ap)[0];
      *(float4*)&vv[4]  = ((const float4*)ap)[1];
      *(float4*)&vv[8]  = ((const float4*)ap)[2];
      *(float4*)&vv[12] = ((const float4*)ap)[3];
      u32 H[8], L[8];
      split16(vv, H, L);
      *(uint4*)(Ah + sr*40 + skh)     = make_uint4(H[0],H[1],H[2],H[3]);
      *(uint4*)(Ah + sr*40 + skh + 8) = make_uint4(H[4],H[5],H[6],H[7]);
      *(uint4*)(Al + sr*40 + skh)     = make_uint4(L[0],L[1],L[2],L[3]);
      *(uint4*)(Al + sr*40 + skh + 8) = make_uint4(L[4],L[5],L[6],L[7]);
    }
    { // B stage: pre-split bf16 copy
      const u16* bp = Bhg + (size_t)(col0+sr)*K + k0 + skh;
      *(uint4*)(Bh + sr*40 + skh)     = ((const uint4*)bp)[0];
      *(uint4*)(Bh + sr*40 + skh + 8) = ((const uint4*)bp)[1];
      const u16* lp = Blg + (size_t)(col0+sr)*K + k0 + skh;
      *(uint4*)(Bl + sr*40 + skh)     = ((const uint4*)lp)[0];
      *(uint4*)(Bl + sr*40 + skh + 8) = ((const uint4*)lp)[1];
    }
    __syncthreads();
    bf16x8 ah[4], al_[4], bh_[4], bl_[4];
    #pragma unroll
    for (int mi = 0; mi < 4; ++mi) {
      ah[mi]  = *(const bf16x8*)(Ah + (wm*64 + mi*16 + l15)*40 + l4*8);
      al_[mi] = *(const bf16x8*)(Al + (wm*64 + mi*16 + l15)*40 + l4*8);
    }
    #pragma unroll
    for (int ni = 0; ni < 4; ++ni) {
      bh_[ni] = *(const bf16x8*)(Bh + (wn*64 + ni*16 + l15)*40 + l4*8);
      bl_[ni] = *(const bf16x8*)(Bl + (wn*64 + ni*16 + l15)*40 + l4*8);
    }
    #pragma unroll
    for (int mi = 0; mi < 4; ++mi)
      #pragma unroll
      for (int ni = 0; ni < 4; ++ni) {
        acc[mi][ni] = __builtin_amdgcn_mfma_f32_16x16x32_bf16(ah[mi], bh_[ni], acc[mi][ni], 0,0,0);
        acc[mi][ni] = __builtin_amdgcn_mfma_f32_16x16x32_bf16(ah[mi], bl_[ni], acc[mi][ni], 0,0,0);
        acc[mi][ni] = __builtin_amdgcn_mfma_f32_16x16x32_bf16(al_[mi], bh_[ni], acc[mi][ni], 0,0,0);
      }
    __syncthreads();
  }
  #pragma unroll
  for (int mi = 0; mi < 4; ++mi)
    #pragma unroll
    for (int r = 0; r < 4; ++r) {
      int row = row0 + wm*64 + mi*16 + l4*4 + r;
      #pragma unroll
      for (int ni = 0; ni < 4; ++ni) {
        int col = col0 + wn*64 + ni*16 + l15;
        float vv = acc[mi][ni][r] + bias[col];
        if (RESID) vv += resid[(size_t)row*N + col];
        C[(size_t)row*N + col] = vv;
      }
    }
}

// ---------------- RoPE trig table (f64) ------------------------------------
__global__ void tb_trig(float* __restrict__ tab) {
  int t = blockIdx.x, d = threadIdx.x;
  double theta = pow(10000.0, -(double)d / 32.0);
  double ang = (double)t * theta;
  tab[(t*32 + d)*2 + 0] = (float)cos(ang);
  tab[(t*32 + d)*2 + 1] = (float)sin(ang);
}

// ---------------- qkv -> Q f32, K bf16 hi/lo (all [bh][t][d]), V f32 -------
__global__ __launch_bounds__(256) void tb_rope2(const float* __restrict__ qkv,
    const float* __restrict__ tab, float* __restrict__ Qf, u16* __restrict__ Khg,
    u16* __restrict__ Klg, float* __restrict__ Vf) {
  int n = blockIdx.x;
  int b = n >> 10, t = n & 1023;
  const float* src = qkv + (size_t)n * 3072;
  for (int idx = threadIdx.x; idx < 512; idx += 256) {
    int h = idx >> 5, d = idx & 31;
    float ca = tab[(t*32+d)*2], sa = tab[(t*32+d)*2+1];
    size_t base = ((size_t)(b*NHEAD + h) * T_LEN + t) * HDIM;
    { float x1 = src[h*64 + d], x2 = src[h*64 + d + 32];
      Qf[base + d]      = x1*ca - x2*sa;
      Qf[base + d + 32] = x1*sa + x2*ca; }
    { float x1 = src[1024 + h*64 + d], x2 = src[1024 + h*64 + d + 32];
      float k1 = x1*ca - x2*sa, k2 = x1*sa + x2*ca;
      u16 h1 = f2bf(k1), h2 = f2bf(k2);
      Khg[base + d] = h1;      Khg[base + d + 32] = h2;
      Klg[base + d] = f2bf(k1 - bf2f(h1));
      Klg[base + d + 32] = f2bf(k2 - bf2f(h2)); }
  }
  for (int c = threadIdx.x; c < 1024; c += 256) {
    int h = c >> 6, d = c & 63;
    Vf[((size_t)(b*NHEAD + h) * T_LEN + t) * HDIM + d] = src[2048 + c];
  }
}

// ---------------- V transpose+split: [bh][t][d] f32 -> [bh][d][t] bf16 -----
__global__ __launch_bounds__(256) void tb_vt(const float* __restrict__ Vf,
    u16* __restrict__ Vh, u16* __restrict__ Vl) {
  __shared__ float Tf[64*68];
  int t0 = blockIdx.x * 64, bh = blockIdx.y;
  const float* Vb = Vf + (size_t)bh * (T_LEN*HDIM);
  int tid = threadIdx.x, r = tid >> 2, c = tid & 3;
  const float* vp = Vb + (size_t)(t0+r)*HDIM + c*16;
  float vv[16];
  *(float4*)&vv[0]  = ((const float4*)vp)[0];
  *(float4*)&vv[4]  = ((const float4*)vp)[1];
  *(float4*)&vv[8]  = ((const float4*)vp)[2];
  *(float4*)&vv[12] = ((const float4*)vp)[3];
  #pragma unroll
  for (int j = 0; j < 16; ++j) Tf[(c*16+j)*68 + r] = vv[j];
  __syncthreads();
  int d = tid >> 2, tc = tid & 3;
  float tv[16];
  #pragma unroll
  for (int j = 0; j < 16; ++j) tv[j] = Tf[d*68 + tc*16 + j];
  u32 H[8], L[8];
  split16(tv, H, L);
  u16* oh = Vh + (size_t)bh*(HDIM*T_LEN) + (size_t)d*T_LEN + t0 + tc*16;
  u16* ol = Vl + (size_t)bh*(HDIM*T_LEN) + (size_t)d*T_LEN + t0 + tc*16;
  *(uint4*)oh       = make_uint4(H[0],H[1],H[2],H[3]);
  *(uint4*)(oh + 8) = make_uint4(H[4],H[5],H[6],H[7]);
  *(uint4*)ol       = make_uint4(L[0],L[1],L[2],L[3]);
  *(uint4*)(ol + 8) = make_uint4(L[4],L[5],L[6],L[7]);
}

// ---------------- MFMA flash attention (split-bf16, fp32 accuracy) ---------
__global__ __launch_bounds__(256) void tb_attn_mfma(const float* __restrict__ Qf,
    const u16* __restrict__ Khg, const u16* __restrict__ Klg,
    const u16* __restrict__ Vhg, const u16* __restrict__ Vlg,
    float* __restrict__ Og) {
  __shared__ __align__(16) u16 Kh[64*72], Kl[64*72];
  __shared__ __align__(16) u16 Vh[64*72], Vl[64*72];
  __shared__ __align__(16) u16 Ph[64*72], Pl[64*72];
  int qt = blockIdx.x, bh = blockIdx.y;
  int tid = threadIdx.x, lane = tid & 63, w = tid >> 6;
  int l15 = lane & 15, l4 = lane >> 4;
  int b = bh >> 4, h = bh & 15;
  const float* Qb = Qf + (size_t)bh * (T_LEN*HDIM);
  const u16* Khb = Khg + (size_t)bh * (T_LEN*HDIM);
  const u16* Klb = Klg + (size_t)bh * (T_LEN*HDIM);
  const u16* Vhb = Vhg + (size_t)bh * (HDIM*T_LEN);
  const u16* Vlb = Vlg + (size_t)bh * (HDIM*T_LEN);
  int q0 = qt * 64;
  int qrow = q0 + w*16 + l15;
  // Q fragments (hi/lo), in registers for the whole kernel
  bf16x8 qh[2], ql[2];
  #pragma unroll
  for (int ks = 0; ks < 2; ++ks) {
    const float* qp = Qb + (size_t)qrow*HDIM + ks*32 + l4*8;
    float vv[8];
    *(float4*)&vv[0] = ((const float4*)qp)[0];
    *(float4*)&vv[4] = ((const float4*)qp)[1];
    u32 H[4], L[4];
    #pragma unroll
    for (int j = 0; j < 4; ++j) {
      float a = vv[2*j], bb = vv[2*j+1];
      u16 ha = f2bf(a), hb = f2bf(bb);
      u16 la = f2bf(a - bf2f(ha)), lb = f2bf(bb - bf2f(hb));
      H[j] = (u32)ha | ((u32)hb << 16);
      L[j] = (u32)la | ((u32)lb << 16);
    }
    b8u th, tl;
    th.u = make_uint4(H[0],H[1],H[2],H[3]);
    tl.u = make_uint4(L[0],L[1],L[2],L[3]);
    qh[ks] = th.b; ql[ks] = tl.b;
  }
  int qg[4];
  #pragma unroll
  for (int r = 0; r < 4; ++r) qg[r] = q0 + w*16 + l4*4 + r;
  float mrow[4], lrow[4];
  f32x4 oacc[4];
  f32x4 zero = {0.f,0.f,0.f,0.f};
  #pragma unroll
  for (int r = 0; r < 4; ++r) { mrow[r] = -1e30f; lrow[r] = 0.f; }
  #pragma unroll
  for (int d = 0; d < 4; ++d) oacc[d] = zero;

  int sr = tid >> 2, sc = tid & 3;
  for (int kt = 0; kt <= qt; ++kt) {
    int k0 = kt * 64;
    __syncthreads();
    { // stage K [key][d] and V [d][key] (pre-split bf16 copies)
      const u16* kp = Khb + (size_t)(k0+sr)*HDIM + sc*16;
      *(uint4*)(Kh + sr*72 + sc*16)     = ((const uint4*)kp)[0];
      *(uint4*)(Kh + sr*72 + sc*16 + 8) = ((const uint4*)kp)[1];
      const u16* kl2 = Klb + (size_t)(k0+sr)*HDIM + sc*16;
      *(uint4*)(Kl + sr*72 + sc*16)     = ((const uint4*)kl2)[0];
      *(uint4*)(Kl + sr*72 + sc*16 + 8) = ((const uint4*)kl2)[1];
      const u16* vp = Vhb + (size_t)sr*T_LEN + k0 + sc*16;
      *(uint4*)(Vh + sr*72 + sc*16)     = ((const uint4*)vp)[0];
      *(uint4*)(Vh + sr*72 + sc*16 + 8) = ((const uint4*)vp)[1];
      const u16* vl2 = Vlb + (size_t)sr*T_LEN + k0 + sc*16;
      *(uint4*)(Vl + sr*72 + sc*16)     = ((const uint4*)vl2)[0];
      *(uint4*)(Vl + sr*72 + sc*16 + 8) = ((const uint4*)vl2)[1];
    }
    __syncthreads();
    // S = Q K^T (3-MFMA split)
    f32x4 sacc[4];
    #pragma unroll
    for (int ni = 0; ni < 4; ++ni) {
      sacc[ni] = zero;
      #pragma unroll
      for (int ks = 0; ks < 2; ++ks) {
        bf16x8 kh_ = *(const bf16x8*)(Kh + (ni*16 + l15)*72 + ks*32 + l4*8);
        bf16x8 kl_ = *(const bf16x8*)(Kl + (ni*16 + l15)*72 + ks*32 + l4*8);
        sacc[ni] = __builtin_amdgcn_mfma_f32_16x16x32_bf16(qh[ks], kh_, sacc[ni], 0,0,0);
        sacc[ni] = __builtin_amdgcn_mfma_f32_16x16x32_bf16(qh[ks], kl_, sacc[ni], 0,0,0);
        sacc[ni] = __builtin_amdgcn_mfma_f32_16x16x32_bf16(ql[ks], kh_, sacc[ni], 0,0,0);
      }
    }
    // scale + causal mask
    bool diag = (kt == qt);
    float sv[4][4];
    #pragma unroll
    for (int ni = 0; ni < 4; ++ni)
      #pragma unroll
      for (int r = 0; r < 4; ++r) {
        float s = sacc[ni][r] * 0.125f;
        if (diag && (k0 + ni*16 + l15 > qg[r])) s = -1e30f;
        sv[ni][r] = s;
      }
    // online softmax
    float mt[4];
    #pragma unroll
    for (int r = 0; r < 4; ++r)
      mt[r] = fmaxf(fmaxf(sv[0][r], sv[1][r]), fmaxf(sv[2][r], sv[3][r]));
    #pragma unroll
    for (int off = 1; off < 16; off <<= 1)
      #pragma unroll
      for (int r = 0; r < 4; ++r) mt[r] = fmaxf(mt[r], __shfl_xor(mt[r], off));
    float al[4];
    #pragma unroll
    for (int r = 0; r < 4; ++r) {
      float mn = fmaxf(mrow[r], mt[r]);
      al[r] = expf(mrow[r] - mn);
      mrow[r] = mn;
    }
    float ls[4] = {0.f,0.f,0.f,0.f};
    #pragma unroll
    for (int ni = 0; ni < 4; ++ni)
      #pragma unroll
      for (int r = 0; r < 4; ++r) {
        float p = expf(sv[ni][r] - mrow[r]);
        u16 ph2 = f2bf(p);
        int qrl = w*16 + l4*4 + r;
        Ph[qrl*72 + ni*16 + l15] = ph2;
        Pl[qrl*72 + ni*16 + l15] = f2bf(p - bf2f(ph2));
        ls[r] += p;
      }
    #pragma unroll
    for (int off = 1; off < 16; off <<= 1)
      #pragma unroll
      for (int r = 0; r < 4; ++r) ls[r] += __shfl_xor(ls[r], off);
    #pragma unroll
    for (int r = 0; r < 4; ++r) lrow[r] = lrow[r]*al[r] + ls[r];
    #pragma unroll
    for (int d = 0; d < 4; ++d)
      #pragma unroll
      for (int r = 0; r < 4; ++r) oacc[d][r] *= al[r];
    // O += P V  (P via LDS bounce to A-fragment layout; wave-local rows)
    bf16x8 ph_[2], pl_[2];
    #pragma unroll
    for (int ks = 0; ks < 2; ++ks) {
      ph_[ks] = *(const bf16x8*)(Ph + (w*16 + l15)*72 + ks*32 + l4*8);
      pl_[ks] = *(const bf16x8*)(Pl + (w*16 + l15)*72 + ks*32 + l4*8);
    }
    #pragma unroll
    for (int dblk = 0; dblk < 4; ++dblk)
      #pragma unroll
      for (int ks = 0; ks < 2; ++ks) {
        bf16x8 vh_ = *(const bf16x8*)(Vh + (dblk*16 + l15)*72 + ks*32 + l4*8);
        bf16x8 vl_ = *(const bf16x8*)(Vl + (dblk*16 + l15)*72 + ks*32 + l4*8);
        oacc[dblk] = __builtin_amdgcn_mfma_f32_16x16x32_bf16(ph_[ks], vh_, oacc[dblk], 0,0,0);
        oacc[dblk] = __builtin_amdgcn_mfma_f32_16x16x32_bf16(ph_[ks], vl_, oacc[dblk], 0,0,0);
        oacc[dblk] = __builtin_amdgcn_mfma_f32_16x16x32_bf16(pl_[ks], vh_, oacc[dblk], 0,0,0);
      }
  }
  #pragma unroll
  for (int dblk = 0; dblk < 4; ++dblk)
    #pragma unroll
    for (int r = 0; r < 4; ++r) {
      int q = qg[r];
      int d = dblk*16 + l15;
      Og[((size_t)b * T_LEN + q) * DMODEL + h * HDIM + d] = oacc[dblk][r] / lrow[r];
    }
}

// ---------------- router: f64 logits, top-2 --------------------------------
__global__ __launch_bounds__(64) void tb_gating(const float* __restrict__ xn2,
    const float* __restrict__ wg, const float* __restrict__ bg,
    int* __restrict__ top_idx, float* __restrict__ gate_w, int* __restrict__ counts) {
  int t = blockIdx.x, lane = threadIdx.x;
  const float* xr = xn2 + (size_t)t * DMODEL;
  double part[8];
  #pragma unroll
  for (int e = 0; e < 8; ++e) part[e] = 0.0;
  for (int i = lane; i < DMODEL; i += 64) {
    double xv = (double)xr[i];
    const float* wr = wg + (size_t)i * 8;
    #pragma unroll
    for (int e = 0; e < 8; ++e) part[e] += xv * (double)wr[e];
  }
  #pragma unroll
  for (int e = 0; e < 8; ++e)
    for (int off = 32; off; off >>= 1) part[e] += __shfl_xor(part[e], off);
  if (lane == 0) {
    double lg[8];
    for (int e = 0; e < 8; ++e) lg[e] = part[e] + (double)bg[e];
    int i1 = 0;
    for (int e = 1; e < 8; ++e) if (lg[e] > lg[i1]) i1 = e;
    int i2 = (i1 == 0) ? 1 : 0;
    for (int e = 0; e < 8; ++e) if (e != i1 && lg[e] > lg[i2]) i2 = e;
    double e2 = exp(lg[i2] - lg[i1]);
    double den = 1.0 + e2;
    top_idx[t*2] = i1; top_idx[t*2+1] = i2;
    gate_w[t*2] = (float)(1.0/den); gate_w[t*2+1] = (float)(e2/den);
    atomicAdd(&counts[i1], 1); atomicAdd(&counts[i2], 1);
  }
}

__global__ void tb_scan(const int* __restrict__ counts, int* __restrict__ offs,
    int* __restrict__ cursor, float* __restrict__ aux_out) {
  if (threadIdx.x == 0) {
    int off = 0; float aux = 0.f;
    for (int e = 0; e < 8; ++e) {
      offs[e] = off; cursor[e] = off; off += counts[e];
      float fr = (float)counts[e] / 4096.0f - 0.125f;
      aux += fr * fr;
    }
    aux_out[0] = aux;
  }
}

__global__ __launch_bounds__(128) void tb_gather(const u16* __restrict__ xn2b,
    const int* __restrict__ top_idx, int* __restrict__ cursor,
    int* __restrict__ slot_of, u16* __restrict__ Xg) {
  int t = blockIdx.x;
  __shared__ int sl[2];
  if (threadIdx.x < 2) {
    int e = top_idx[t*2 + threadIdx.x];
    int s = atomicAdd(&cursor[e], 1);
    sl[threadIdx.x] = s;
    slot_of[t*2 + threadIdx.x] = s;
  }
  __syncthreads();
  uint4 v = *(const uint4*)(xn2b + (size_t)t * DMODEL + threadIdx.x * 8);
  *(uint4*)(Xg + (size_t)sl[0] * DMODEL + threadIdx.x * 8) = v;
  *(uint4*)(Xg + (size_t)sl[1] * DMODEL + threadIdx.x * 8) = v;
}

// ---------------- grouped MoE GEMM (unchanged from round 1) ----------------
template<int MODE>
__global__ __launch_bounds__(256) void tb_moe_gemm(const u16* __restrict__ Ag,
    const float* __restrict__ Wf, const float* __restrict__ bias_b,
    const u16* __restrict__ Hprev, u16* __restrict__ out_b, float* __restrict__ out_f,
    const int* __restrict__ counts, const int* __restrict__ offs, int K, int N) {
  int e = blockIdx.z;
  int cnt = counts[e];
  if ((int)blockIdx.y * 128 >= cnt) return;
  int row0 = offs[e] + blockIdx.y * 128;
  int rend = offs[e] + cnt;
  int col0 = blockIdx.x * 128;
  const float* Bw = Wf + (size_t)e * K * N;
  const float* bias = bias_b + (size_t)e * N;
  __shared__ __align__(16) u16 As[128*40];
  __shared__ __align__(16) u16 Bs[128*40];
  int tid = threadIdx.x;
  int lane = tid & 63, wave = tid >> 6;
  int wm = wave >> 1, wn = wave & 1;
  int l15 = lane & 15, l4 = lane >> 4;
  f32x4 zero = {0.f, 0.f, 0.f, 0.f};
  f32x4 acc[4][4];
  #pragma unroll
  for (int i=0;i<4;++i) for (int j=0;j<4;++j) acc[i][j] = zero;
  for (int k0 = 0; k0 < K; k0 += 32) {
    #pragma unroll
    for (int p = 0; p < 2; ++p) {
      int r = (tid >> 2) + p * 64, kk = (tid & 3) * 8;
      uint4 v = make_uint4(0,0,0,0);
      if (row0 + r < rend) v = *(const uint4*)(Ag + (size_t)(row0 + r) * K + k0 + kk);
      *(uint4*)(As + r*40 + kk) = v;
    }
    #pragma unroll
    for (int p = 0; p < 4; ++p) {
      int kk = (tid >> 5) + p * 8, n4 = (tid & 31) * 4;
      float4 v = *(const float4*)(Bw + (size_t)(k0 + kk) * N + col0 + n4);
      Bs[(n4+0)*40 + kk] = f2bf(v.x);
      Bs[(n4+1)*40 + kk] = f2bf(v.y);
      Bs[(n4+2)*40 + kk] = f2bf(v.z);
      Bs[(n4+3)*40 + kk] = f2bf(v.w);
    }
    __syncthreads();
    bf16x8 af[4], bfr[4];
    #pragma unroll
    for (int mi = 0; mi < 4; ++mi)
      af[mi] = *(const bf16x8*)(As + (wm*64 + mi*16 + l15)*40 + l4*8);
    #pragma unroll
    for (int ni = 0; ni < 4; ++ni)
      bfr[ni] = *(const bf16x8*)(Bs + (wn*64 + ni*16 + l15)*40 + l4*8);
    #pragma unroll
    for (int mi = 0; mi < 4; ++mi)
      #pragma unroll
      for (int ni = 0; ni < 4; ++ni)
        acc[mi][ni] = __builtin_amdgcn_mfma_f32_16x16x32_bf16(af[mi], bfr[ni], acc[mi][ni], 0, 0, 0);
    __syncthreads();
  }
  #pragma unroll
  for (int mi = 0; mi < 4; ++mi) {
    #pragma unroll
    for (int r = 0; r < 4; ++r) {
      int row = row0 + wm*64 + mi*16 + l4*4 + r;
      if (row >= rend) continue;
      #pragma unroll
      for (int ni = 0; ni < 4; ++ni) {
        int col = col0 + wn*64 + ni*16 + l15;
        float vv = acc[mi][ni][r] + bias[col];
        size_t oi = (size_t)row * N + col;
        if (MODE == 0)      out_b[oi] = f2bf(vv / (1.f + expf(-vv)));
        else if (MODE == 1) out_b[oi] = f2bf(bf2f(Hprev[oi]) * vv);
        else                out_f[oi] = vv;
      }
    }
  }
}

__global__ __launch_bounds__(256) void tb_combine(const float* __restrict__ x1,
    const float* __restrict__ outp, const int* __restrict__ slot_of,
    const float* __restrict__ gate_w, float* __restrict__ out) {
  int t = blockIdx.x;
  int s0 = slot_of[t*2], s1 = slot_of[t*2+1];
  float g0 = gate_w[t*2], g1 = gate_w[t*2+1];
  int c = threadIdx.x * 4;
  float4 a  = *(const float4*)(x1   + (size_t)t *DMODEL + c);
  float4 p0 = *(const float4*)(outp + (size_t)s0*DMODEL + c);
  float4 p1 = *(const float4*)(outp + (size_t)s1*DMODEL + c);
  float4 o;
  o.x = a.x + g0*p0.x + g1*p1.x;
  o.y = a.y + g0*p0.y + g1*p1.y;
  o.z = a.z + g0*p0.z + g1*p1.z;
  o.w = a.w + g0*p0.w + g1*p1.w;
  *(float4*)(out + (size_t)t*DMODEL + c) = o;
}

extern "C" void kernel_launch(void* const* d_in, const int* in_sizes, int n_in,
                              void* d_out, int out_size, void* d_ws, size_t ws_size,
                              hipStream_t stream) {
  const float* x      = (const float*)d_in[0];
  const float* w_qkv  = (const float*)d_in[1];
  const float* b_qkv  = (const float*)d_in[2];
  const float* w_out  = (const float*)d_in[3];
  const float* b_out  = (const float*)d_in[4];
  const float* scale1 = (const float*)d_in[5];
  const float* scale2 = (const float*)d_in[6];
  const float* w_gate = (const float*)d_in[7];
  const float* b_gate = (const float*)d_in[8];
  const float* w1     = (const float*)d_in[9];
  const float* b1     = (const float*)d_in[10];
  const float* w2     = (const float*)d_in[11];
  const float* b2     = (const float*)d_in[12];
  const float* wp     = (const float*)d_in[13];
  const float* bp     = (const float*)d_in[14];
  float* out = (float*)d_out;

  char* ws = (char*)d_ws;
  const size_t MB = 1024 * 1024;
  // Phase-overlaid workspace (~105MB peak):
  float* XN1  = (float*)(ws + 0*MB);    // 8MB   rms1 out; dead after QKV gemm
  u16*   XG   = (u16*)  (ws + 0*MB);    // 8MB   (overlay XN1)
  float* X1   = (float*)(ws + 8*MB);    // 8MB
  float* XN2F = (float*)(ws + 16*MB);   // 8MB
  u16*   XN2B = (u16*)  (ws + 24*MB);   // 4MB
  float* QKV  = (float*)(ws + 28*MB);   // 24MB; dead after rope
  u16*   HB   = (u16*)  (ws + 28*MB);   // 32MB  (overlay QKV+Qf)
  float* Qf   = (float*)(ws + 52*MB);   // 8MB ; dead after attn
  float* Vf   = (float*)(ws + 60*MB);   // 8MB ; dead after vt
  float* OUTP = (float*)(ws + 60*MB);   // 16MB  (overlay Vf)
  u16*   Wqh  = (u16*)  (ws + 76*MB);   // 6MB ; dead after QKV gemm
  u16*   Wql  = (u16*)  (ws + 82*MB);   // 6MB
  u16*   Khg  = (u16*)  (ws + 76*MB);   // 4MB   (overlay Wqh)
  u16*   Klg  = (u16*)  (ws + 80*MB);   // 4MB
  u16*   Vth  = (u16*)  (ws + 84*MB);   // 4MB   (overlay Wql tail)
  u16*   Vtl  = (u16*)  (ws + 88*MB);   // 4MB
  float* Ob   = (float*)(ws + 92*MB);   // 8MB
  u16*   Woh  = (u16*)  (ws + 100*MB);  // 2MB
  u16*   Wol  = (u16*)  (ws + 102*MB);  // 2MB
  char*  GT   = ws + 104*MB;
  int*   top_idx = (int*)  (GT);
  float* gate_w  = (float*)(GT + 16*1024);
  int*   slot_of = (int*)  (GT + 32*1024);
  int*   counts  = (int*)  (GT + 48*1024);
  int*   offs    = (int*)  (GT + 48*1024 + 64);
  int*   cursor  = (int*)  (GT + 48*1024 + 128);
  float* trig    = (float*)(GT + 64*1024);

  hipMemsetAsync(counts, 0, 32, stream);
  tb_trig<<<1024, 32, 0, stream>>>(trig);
  tb_wsplit<1><<<dim3(48,16,1), 256, 0, stream>>>(w_qkv, Wqh, Wql, 1024, 3072);
  tb_wsplit<1><<<dim3(16,16,1), 256, 0, stream>>>(w_out, Woh, Wol, 1024, 1024);
  tb_rms<0><<<2048, 256, 0, stream>>>(x, scale1, XN1, nullptr);
  tb_gemm_sp<0><<<dim3(24,16), 256, 0, stream>>>(XN1, Wqh, Wql, b_qkv, nullptr, QKV, 2048, 3072, 1024);
  tb_rope2<<<2048, 256, 0, stream>>>(QKV, trig, Qf, Khg, Klg, Vf);
  tb_vt<<<dim3(16,32), 256, 0, stream>>>(Vf, Vth, Vtl);
  tb_attn_mfma<<<dim3(16,32), 256, 0, stream>>>(Qf, Khg, Klg, Vth, Vtl, Ob);
  tb_gemm_sp<1><<<dim3(8,16), 256, 0, stream>>>(Ob, Woh, Wol, b_out, x, X1, 2048, 1024, 1024);
  tb_rms<1><<<2048, 256, 0, stream>>>(X1, scale2, XN2F, XN2B);
  tb_gating<<<2048, 64, 0, stream>>>(XN2F, w_gate, b_gate, top_idx, gate_w, counts);
  tb_scan<<<1, 64, 0, stream>>>(counts, offs, cursor, out + (size_t)NTOK*DMODEL);
  tb_gather<<<2048, 128, 0, stream>>>(XN2B, top_idx, cursor, slot_of, XG);
  tb_moe_gemm<0><<<dim3(32,16,8), 256, 0, stream>>>(XG, w1, b1, nullptr, HB, nullptr, counts, offs, 1024, 4096);
  tb_moe_gemm<1><<<dim3(32,16,8), 256, 0, stream>>>(XG, w2, b2, HB, HB, nullptr, counts, offs, 1024, 4096);
  tb_moe_gemm<2><<<dim3(8,16,8), 256, 0, stream>>>(HB, wp, bp, nullptr, nullptr, OUTP, counts, offs, 4096, 1024);
  tb_combine<<<2048, 256, 0, stream>>>(X1, OUTP, slot_of, gate_w, out);
}

// Round 3
// 739.977 us; speedup vs baseline: 2.9185x; 1.5953x over previous
//
#include <hip/hip_runtime.h>
#include <math.h>

typedef unsigned short u16;
typedef unsigned int   u32;
typedef float f32x4 __attribute__((ext_vector_type(4)));
typedef __bf16 bf16x8 __attribute__((ext_vector_type(8)));

#define T_LEN  1024
#define DMODEL 1024
#define NTOK   2048
#define NHEAD  16
#define HDIM   64
#define NEXP   8
#define FFDIM  4096

__device__ __forceinline__ u16 f2bf(float f) {          // RNE
  union { float f; u32 u; } v; v.f = f;
  u32 r = v.u + 0x7FFFu + ((v.u >> 16) & 1u);
  return (u16)(r >> 16);
}
__device__ __forceinline__ float bf2f(u16 h) {
  union { u32 u; float f; } v; v.u = ((u32)h) << 16; return v.f;
}
union b8u { uint4 u; bf16x8 b; };

// split 16 f32 -> 8 packed u32 hi + 8 packed u32 lo
__device__ __forceinline__ void split16(const float* src, u32* H, u32* L) {
  #pragma unroll
  for (int j = 0; j < 8; ++j) {
    float a = src[2*j], b = src[2*j+1];
    u16 ha = f2bf(a), hb = f2bf(b);
    u16 la = f2bf(a - bf2f(ha)), lb = f2bf(b - bf2f(hb));
    H[j] = (u32)ha | ((u32)hb << 16);
    L[j] = (u32)la | ((u32)lb << 16);
  }
}

// ---------------- RMSNorm (f64 accumulate) ---------------------------------
template<int WRITE_B>
__global__ __launch_bounds__(256) void tb_rms(const float* __restrict__ x,
    const float* __restrict__ scale, float* __restrict__ out_f, u16* __restrict__ out_b) {
  int t = blockIdx.x, tid = threadIdx.x;
  const float* xr = x + (size_t)t * DMODEL;
  float4 v = *(const float4*)(xr + tid * 4);
  double ss = (double)v.x*v.x + (double)v.y*v.y + (double)v.z*v.z + (double)v.w*v.w;
  #pragma unroll
  for (int off = 32; off; off >>= 1) ss += __shfl_xor(ss, off);
  __shared__ double red[4];
  if ((tid & 63) == 0) red[tid >> 6] = ss;
  __syncthreads();
  double denom = sqrt((red[0]+red[1]+red[2]+red[3]) / (double)DMODEL) + 1e-5;
  float4 sc = *(const float4*)(scale + tid * 4);
  float y0 = (float)((double)v.x / denom * (double)sc.x);
  float y1 = (float)((double)v.y / denom * (double)sc.y);
  float y2 = (float)((double)v.z / denom * (double)sc.z);
  float y3 = (float)((double)v.w / denom * (double)sc.w);
  *(float4*)(out_f + (size_t)t*DMODEL + tid*4) = make_float4(y0,y1,y2,y3);
  if (WRITE_B) {
    u16* ob = out_b + (size_t)t*DMODEL + tid*4;
    ob[0]=f2bf(y0); ob[1]=f2bf(y1); ob[2]=f2bf(y2); ob[3]=f2bf(y3);
  }
}

// ------- weight pre-split+transpose: W[k][n] f32 -> Wt[n][k] bf16 (hi[,lo]) -
template<int HILO>
__global__ __launch_bounds__(256) void tb_wsplit(const float* __restrict__ W,
    u16* __restrict__ Wh, u16* __restrict__ Wl, int K, int N) {
  __shared__ float Tf[64*68];
  size_t eo = (size_t)blockIdx.z * (size_t)K * N;
  const float* Wb = W + eo;
  int n0 = blockIdx.x*64, k0 = blockIdx.y*64;
  int tid = threadIdx.x;
  int r = tid >> 2, c = tid & 3;
  const float* wp = Wb + (size_t)(k0+r)*N + n0 + c*16;
  float vv[16];
  *(float4*)&vv[0]  = ((const float4*)wp)[0];
  *(float4*)&vv[4]  = ((const float4*)wp)[1];
  *(float4*)&vv[8]  = ((const float4*)wp)[2];
  *(float4*)&vv[12] = ((const float4*)wp)[3];
  #pragma unroll
  for (int j = 0; j < 16; ++j) Tf[(c*16+j)*68 + r] = vv[j];
  __syncthreads();
  int n = tid >> 2, kc = tid & 3;
  float tv[16];
  #pragma unroll
  for (int j = 0; j < 16; ++j) tv[j] = Tf[n*68 + kc*16 + j];
  u32 H[8], L[8];
  split16(tv, H, L);
  u16* oh = Wh + eo + (size_t)(n0+n)*K + k0 + kc*16;
  *(uint4*)oh       = make_uint4(H[0],H[1],H[2],H[3]);
  *(uint4*)(oh + 8) = make_uint4(H[4],H[5],H[6],H[7]);
  if (HILO) {
    u16* ol = Wl + eo + (size_t)(n0+n)*K + k0 + kc*16;
    *(uint4*)ol       = make_uint4(L[0],L[1],L[2],L[3]);
    *(uint4*)(ol + 8) = make_uint4(L[4],L[5],L[6],L[7]);
  }
}

// ---------------- split-bf16 MFMA GEMM: C = A(f32) * Wt + bias [+resid] ----
template<int RESID>
__global__ __launch_bounds__(256) void tb_gemm_sp(const float* __restrict__ A,
    const u16* __restrict__ Bhg, const u16* __restrict__ Blg,
    const float* __restrict__ bias, const float* __restrict__ resid,
    float* __restrict__ C, int M, int N, int K) {
  __shared__ __align__(16) u16 Ah[128*40], Al[128*40], Bh[128*40], Bl[128*40];
  int tid = threadIdx.x;
  int row0 = blockIdx.y * 128, col0 = blockIdx.x * 128;
  int lane = tid & 63, wave = tid >> 6;
  int wm = wave >> 1, wn = wave & 1;
  int l15 = lane & 15, l4 = lane >> 4;
  int sr = tid >> 1, skh = (tid & 1) * 16;
  f32x4 zero = {0.f,0.f,0.f,0.f};
  f32x4 acc[4][4];
  #pragma unroll
  for (int i=0;i<4;++i) for (int j=0;j<4;++j) acc[i][j] = zero;
  for (int k0 = 0; k0 < K; k0 += 32) {
    { // A stage: f32 -> hi/lo bf16
      const float* ap = A + (size_t)(row0+sr)*K + k0 + skh;
      float vv[16];
      *(float4*)&vv[0]  = ((const float4*)ap)[0];
      *(float4*)&vv[4]  = ((const float4*)ap)[1];
      *(float4*)&vv[8]  = ((const float4*)ap)[2];
      *(float4*)&vv[12] = ((const float4*)ap)[3];
      u32 H[8], L[8];
      split16(vv, H, L);
      *(uint4*)(Ah + sr*40 + skh)     = make_uint4(H[0],H[1],H[2],H[3]);
      *(uint4*)(Ah + sr*40 + skh + 8) = make_uint4(H[4],H[5],H[6],H[7]);
      *(uint4*)(Al + sr*40 + skh)     = make_uint4(L[0],L[1],L[2],L[3]);
      *(uint4*)(Al + sr*40 + skh + 8) = make_uint4(L[4],L[5],L[6],L[7]);
    }
    { // B stage: pre-split bf16 copy
      const u16* bp = Bhg + (size_t)(col0+sr)*K + k0 + skh;
      *(uint4*)(Bh + sr*40 + skh)     = ((const uint4*)bp)[0];
      *(uint4*)(Bh + sr*40 + skh + 8) = ((const uint4*)bp)[1];
      const u16* lp = Blg + (size_t)(col0+sr)*K + k0 + skh;
      *(uint4*)(Bl + sr*40 + skh)     = ((const uint4*)lp)[0];
      *(uint4*)(Bl + sr*40 + skh + 8) = ((const uint4*)lp)[1];
    }
    __syncthreads();
    bf16x8 ah[4], al_[4], bh_[4], bl_[4];
    #pragma unroll
    for (int mi = 0; mi < 4; ++mi) {
      ah[mi]  = *(const bf16x8*)(Ah + (wm*64 + mi*16 + l15)*40 + l4*8);
      al_[mi] = *(const bf16x8*)(Al + (wm*64 + mi*16 + l15)*40 + l4*8);
    }
    #pragma unroll
    for (int ni = 0; ni < 4; ++ni) {
      bh_[ni] = *(const bf16x8*)(Bh + (wn*64 + ni*16 + l15)*40 + l4*8);
      bl_[ni] = *(const bf16x8*)(Bl + (wn*64 + ni*16 + l15)*40 + l4*8);
    }
    #pragma unroll
    for (int mi = 0; mi < 4; ++mi)
      #pragma unroll
      for (int ni = 0; ni < 4; ++ni) {
        acc[mi][ni] = __builtin_amdgcn_mfma_f32_16x16x32_bf16(ah[mi], bh_[ni], acc[mi][ni], 0,0,0);
        acc[mi][ni] = __builtin_amdgcn_mfma_f32_16x16x32_bf16(ah[mi], bl_[ni], acc[mi][ni], 0,0,0);
        acc[mi][ni] = __builtin_amdgcn_mfma_f32_16x16x32_bf16(al_[mi], bh_[ni], acc[mi][ni], 0,0,0);
      }
    __syncthreads();
  }
  #pragma unroll
  for (int mi = 0; mi < 4; ++mi)
    #pragma unroll
    for (int r = 0; r < 4; ++r) {
      int row = row0 + wm*64 + mi*16 + l4*4 + r;
      #pragma unroll
      for (int ni = 0; ni < 4; ++ni) {
        int col = col0 + wn*64 + ni*16 + l15;
        float vv = acc[mi][ni][r] + bias[col];
        if (RESID) vv += resid[(size_t)row*N + col];
        C[(size_t)row*N + col] = vv;
      }
    }
}

// ---------------- RoPE trig table (f64) ------------------------------------
__global__ void tb_trig(float* __restrict__ tab) {
  int t = blockIdx.x, d = threadIdx.x;
  double theta = pow(10000.0, -(double)d / 32.0);
  double ang = (double)t * theta;
  tab[(t*32 + d)*2 + 0] = (float)cos(ang);
  tab[(t*32 + d)*2 + 1] = (float)sin(ang);
}

// ---------------- qkv -> Q f32, K bf16 hi/lo (all [bh][t][d]), V f32 -------
__global__ __launch_bounds__(256) void tb_rope2(const float* __restrict__ qkv,
    const float* __restrict__ tab, float* __restrict__ Qf, u16* __restrict__ Khg,
    u16* __restrict__ Klg, float* __restrict__ Vf) {
  int n = blockIdx.x;
  int b = n >> 10, t = n & 1023;
  const float* src = qkv + (size_t)n * 3072;
  for (int idx = threadIdx.x; idx < 512; idx += 256) {
    int h = idx >> 5, d = idx & 31;
    float ca = tab[(t*32+d)*2], sa = tab[(t*32+d)*2+1];
    size_t base = ((size_t)(b*NHEAD + h) * T_LEN + t) * HDIM;
    { float x1 = src[h*64 + d], x2 = src[h*64 + d + 32];
      Qf[base + d]      = x1*ca - x2*sa;
      Qf[base + d + 32] = x1*sa + x2*ca; }
    { float x1 = src[1024 + h*64 + d], x2 = src[1024 + h*64 + d + 32];
      float k1 = x1*ca - x2*sa, k2 = x1*sa + x2*ca;
      u16 h1 = f2bf(k1), h2 = f2bf(k2);
      Khg[base + d] = h1;      Khg[base + d + 32] = h2;
      Klg[base + d] = f2bf(k1 - bf2f(h1));
      Klg[base + d + 32] = f2bf(k2 - bf2f(h2)); }
  }
  for (int c = threadIdx.x; c < 1024; c += 256) {
    int h = c >> 6, d = c & 63;
    Vf[((size_t)(b*NHEAD + h) * T_LEN + t) * HDIM + d] = src[2048 + c];
  }
}

// ---------------- V transpose+split: [bh][t][d] f32 -> [bh][d][t] bf16 -----
__global__ __launch_bounds__(256) void tb_vt(const float* __restrict__ Vf,
    u16* __restrict__ Vh, u16* __restrict__ Vl) {
  __shared__ float Tf[64*68];
  int t0 = blockIdx.x * 64, bh = blockIdx.y;
  const float* Vb = Vf + (size_t)bh * (T_LEN*HDIM);
  int tid = threadIdx.x, r = tid >> 2, c = tid & 3;
  const float* vp = Vb + (size_t)(t0+r)*HDIM + c*16;
  float vv[16];
  *(float4*)&vv[0]  = ((const float4*)vp)[0];
  *(float4*)&vv[4]  = ((const float4*)vp)[1];
  *(float4*)&vv[8]  = ((const float4*)vp)[2];
  *(float4*)&vv[12] = ((const float4*)vp)[3];
  #pragma unroll
  for (int j = 0; j < 16; ++j) Tf[(c*16+j)*68 + r] = vv[j];
  __syncthreads();
  int d = tid >> 2, tc = tid & 3;
  float tv[16];
  #pragma unroll
  for (int j = 0; j < 16; ++j) tv[j] = Tf[d*68 + tc*16 + j];
  u32 H[8], L[8];
  split16(tv, H, L);
  u16* oh = Vh + (size_t)bh*(HDIM*T_LEN) + (size_t)d*T_LEN + t0 + tc*16;
  u16* ol = Vl + (size_t)bh*(HDIM*T_LEN) + (size_t)d*T_LEN + t0 + tc*16;
  *(uint4*)oh       = make_uint4(H[0],H[1],H[2],H[3]);
  *(uint4*)(oh + 8) = make_uint4(H[4],H[5],H[6],H[7]);
  *(uint4*)ol       = make_uint4(L[0],L[1],L[2],L[3]);
  *(uint4*)(ol + 8) = make_uint4(L[4],L[5],L[6],L[7]);
}

// ---------------- MFMA flash attention (split-bf16, fp32 accuracy) ---------
__global__ __launch_bounds__(256) void tb_attn_mfma(const float* __restrict__ Qf,
    const u16* __restrict__ Khg, const u16* __restrict__ Klg,
    const u16* __restrict__ Vhg, const u16* __restrict__ Vlg,
    float* __restrict__ Og) {
  __shared__ __align__(16) u16 Kh[64*72], Kl[64*72];
  __shared__ __align__(16) u16 Vh[64*72], Vl[64*72];
  __shared__ __align__(16) u16 Ph[64*72], Pl[64*72];
  int qt = blockIdx.x, bh = blockIdx.y;
  int tid = threadIdx.x, lane = tid & 63, w = tid >> 6;
  int l15 = lane & 15, l4 = lane >> 4;
  int b = bh >> 4, h = bh & 15;
  const float* Qb = Qf + (size_t)bh * (T_LEN*HDIM);
  const u16* Khb = Khg + (size_t)bh * (T_LEN*HDIM);
  const u16* Klb = Klg + (size_t)bh * (T_LEN*HDIM);
  const u16* Vhb = Vhg + (size_t)bh * (HDIM*T_LEN);
  const u16* Vlb = Vlg + (size_t)bh * (HDIM*T_LEN);
  int q0 = qt * 64;
  int qrow = q0 + w*16 + l15;
  bf16x8 qh[2], ql[2];
  #pragma unroll
  for (int ks = 0; ks < 2; ++ks) {
    const float* qp = Qb + (size_t)qrow*HDIM + ks*32 + l4*8;
    float vv[8];
    *(float4*)&vv[0] = ((const float4*)qp)[0];
    *(float4*)&vv[4] = ((const float4*)qp)[1];
    u32 H[4], L[4];
    #pragma unroll
    for (int j = 0; j < 4; ++j) {
      float a = vv[2*j], bb = vv[2*j+1];
      u16 ha = f2bf(a), hb = f2bf(bb);
      u16 la = f2bf(a - bf2f(ha)), lb = f2bf(bb - bf2f(hb));
      H[j] = (u32)ha | ((u32)hb << 16);
      L[j] = (u32)la | ((u32)lb << 16);
    }
    b8u th, tl;
    th.u = make_uint4(H[0],H[1],H[2],H[3]);
    tl.u = make_uint4(L[0],L[1],L[2],L[3]);
    qh[ks] = th.b; ql[ks] = tl.b;
  }
  int qg[4];
  #pragma unroll
  for (int r = 0; r < 4; ++r) qg[r] = q0 + w*16 + l4*4 + r;
  float mrow[4], lrow[4];
  f32x4 oacc[4];
  f32x4 zero = {0.f,0.f,0.f,0.f};
  #pragma unroll
  for (int r = 0; r < 4; ++r) { mrow[r] = -1e30f; lrow[r] = 0.f; }
  #pragma unroll
  for (int d = 0; d < 4; ++d) oacc[d] = zero;

  int sr = tid >> 2, sc = tid & 3;
  for (int kt = 0; kt <= qt; ++kt) {
    int k0 = kt * 64;
    __syncthreads();
    {
      const u16* kp = Khb + (size_t)(k0+sr)*HDIM + sc*16;
      *(uint4*)(Kh + sr*72 + sc*16)     = ((const uint4*)kp)[0];
      *(uint4*)(Kh + sr*72 + sc*16 + 8) = ((const uint4*)kp)[1];
      const u16* kl2 = Klb + (size_t)(k0+sr)*HDIM + sc*16;
      *(uint4*)(Kl + sr*72 + sc*16)     = ((const uint4*)kl2)[0];
      *(uint4*)(Kl + sr*72 + sc*16 + 8) = ((const uint4*)kl2)[1];
      const u16* vp = Vhb + (size_t)sr*T_LEN + k0 + sc*16;
      *(uint4*)(Vh + sr*72 + sc*16)     = ((const uint4*)vp)[0];
      *(uint4*)(Vh + sr*72 + sc*16 + 8) = ((const uint4*)vp)[1];
      const u16* vl2 = Vlb + (size_t)sr*T_LEN + k0 + sc*16;
      *(uint4*)(Vl + sr*72 + sc*16)     = ((const uint4*)vl2)[0];
      *(uint4*)(Vl + sr*72 + sc*16 + 8) = ((const uint4*)vl2)[1];
    }
    __syncthreads();
    f32x4 sacc[4];
    #pragma unroll
    for (int ni = 0; ni < 4; ++ni) {
      sacc[ni] = zero;
      #pragma unroll
      for (int ks = 0; ks < 2; ++ks) {
        bf16x8 kh_ = *(const bf16x8*)(Kh + (ni*16 + l15)*72 + ks*32 + l4*8);
        bf16x8 kl_ = *(const bf16x8*)(Kl + (ni*16 + l15)*72 + ks*32 + l4*8);
        sacc[ni] = __builtin_amdgcn_mfma_f32_16x16x32_bf16(qh[ks], kh_, sacc[ni], 0,0,0);
        sacc[ni] = __builtin_amdgcn_mfma_f32_16x16x32_bf16(qh[ks], kl_, sacc[ni], 0,0,0);
        sacc[ni] = __builtin_amdgcn_mfma_f32_16x16x32_bf16(ql[ks], kh_, sacc[ni], 0,0,0);
      }
    }
    bool diag = (kt == qt);
    float sv[4][4];
    #pragma unroll
    for (int ni = 0; ni < 4; ++ni)
      #pragma unroll
      for (int r = 0; r < 4; ++r) {
        float s = sacc[ni][r] * 0.125f;
        if (diag && (k0 + ni*16 + l15 > qg[r])) s = -1e30f;
        sv[ni][r] = s;
      }
    float mt[4];
    #pragma unroll
    for (int r = 0; r < 4; ++r)
      mt[r] = fmaxf(fmaxf(sv[0][r], sv[1][r]), fmaxf(sv[2][r], sv[3][r]));
    #pragma unroll
    for (int off = 1; off < 16; off <<= 1)
      #pragma unroll
      for (int r = 0; r < 4; ++r) mt[r] = fmaxf(mt[r], __shfl_xor(mt[r], off));
    float al[4];
    #pragma unroll
    for (int r = 0; r < 4; ++r) {
      float mn = fmaxf(mrow[r], mt[r]);
      al[r] = expf(mrow[r] - mn);
      mrow[r] = mn;
    }
    float ls[4] = {0.f,0.f,0.f,0.f};
    #pragma unroll
    for (int ni = 0; ni < 4; ++ni)
      #pragma unroll
      for (int r = 0; r < 4; ++r) {
        float p = expf(sv[ni][r] - mrow[r]);
        u16 ph2 = f2bf(p);
        int qrl = w*16 + l4*4 + r;
        Ph[qrl*72 + ni*16 + l15] = ph2;
        Pl[qrl*72 + ni*16 + l15] = f2bf(p - bf2f(ph2));
        ls[r] += p;
      }
    #pragma unroll
    for (int off = 1; off < 16; off <<= 1)
      #pragma unroll
      for (int r = 0; r < 4; ++r) ls[r] += __shfl_xor(ls[r], off);
    #pragma unroll
    for (int r = 0; r < 4; ++r) lrow[r] = lrow[r]*al[r] + ls[r];
    #pragma unroll
    for (int d = 0; d < 4; ++d)
      #pragma unroll
      for (int r = 0; r < 4; ++r) oacc[d][r] *= al[r];
    bf16x8 ph_[2], pl_[2];
    #pragma unroll
    for (int ks = 0; ks < 2; ++ks) {
      ph_[ks] = *(const bf16x8*)(Ph + (w*16 + l15)*72 + ks*32 + l4*8);
      pl_[ks] = *(const bf16x8*)(Pl + (w*16 + l15)*72 + ks*32 + l4*8);
    }
    #pragma unroll
    for (int dblk = 0; dblk < 4; ++dblk)
      #pragma unroll
      for (int ks = 0; ks < 2; ++ks) {
        bf16x8 vh_ = *(const bf16x8*)(Vh + (dblk*16 + l15)*72 + ks*32 + l4*8);
        bf16x8 vl_ = *(const bf16x8*)(Vl + (dblk*16 + l15)*72 + ks*32 + l4*8);
        oacc[dblk] = __builtin_amdgcn_mfma_f32_16x16x32_bf16(ph_[ks], vh_, oacc[dblk], 0,0,0);
        oacc[dblk] = __builtin_amdgcn_mfma_f32_16x16x32_bf16(ph_[ks], vl_, oacc[dblk], 0,0,0);
        oacc[dblk] = __builtin_amdgcn_mfma_f32_16x16x32_bf16(pl_[ks], vh_, oacc[dblk], 0,0,0);
      }
  }
  #pragma unroll
  for (int dblk = 0; dblk < 4; ++dblk)
    #pragma unroll
    for (int r = 0; r < 4; ++r) {
      int q = qg[r];
      int d = dblk*16 + l15;
      Og[((size_t)b * T_LEN + q) * DMODEL + h * HDIM + d] = oacc[dblk][r] / lrow[r];
    }
}

// ---------------- router: f64 logits, top-2 --------------------------------
__global__ __launch_bounds__(64) void tb_gating(const float* __restrict__ xn2,
    const float* __restrict__ wg, const float* __restrict__ bg,
    int* __restrict__ top_idx, float* __restrict__ gate_w, int* __restrict__ counts) {
  int t = blockIdx.x, lane = threadIdx.x;
  const float* xr = xn2 + (size_t)t * DMODEL;
  double part[8];
  #pragma unroll
  for (int e = 0; e < 8; ++e) part[e] = 0.0;
  for (int i = lane; i < DMODEL; i += 64) {
    double xv = (double)xr[i];
    const float* wr = wg + (size_t)i * 8;
    #pragma unroll
    for (int e = 0; e < 8; ++e) part[e] += xv * (double)wr[e];
  }
  #pragma unroll
  for (int e = 0; e < 8; ++e)
    for (int off = 32; off; off >>= 1) part[e] += __shfl_xor(part[e], off);
  if (lane == 0) {
    double lg[8];
    for (int e = 0; e < 8; ++e) lg[e] = part[e] + (double)bg[e];
    int i1 = 0;
    for (int e = 1; e < 8; ++e) if (lg[e] > lg[i1]) i1 = e;
    int i2 = (i1 == 0) ? 1 : 0;
    for (int e = 0; e < 8; ++e) if (e != i1 && lg[e] > lg[i2]) i2 = e;
    double e2 = exp(lg[i2] - lg[i1]);
    double den = 1.0 + e2;
    top_idx[t*2] = i1; top_idx[t*2+1] = i2;
    gate_w[t*2] = (float)(1.0/den); gate_w[t*2+1] = (float)(e2/den);
    atomicAdd(&counts[i1], 1); atomicAdd(&counts[i2], 1);
  }
}

__global__ void tb_scan(const int* __restrict__ counts, int* __restrict__ offs,
    int* __restrict__ cursor, float* __restrict__ aux_out) {
  if (threadIdx.x == 0) {
    int off = 0; float aux = 0.f;
    for (int e = 0; e < 8; ++e) {
      offs[e] = off; cursor[e] = off; off += counts[e];
      float fr = (float)counts[e] / 4096.0f - 0.125f;
      aux += fr * fr;
    }
    aux_out[0] = aux;
  }
}

__global__ __launch_bounds__(128) void tb_gather(const u16* __restrict__ xn2b,
    const int* __restrict__ top_idx, int* __restrict__ cursor,
    int* __restrict__ slot_of, u16* __restrict__ Xg) {
  int t = blockIdx.x;
  __shared__ int sl[2];
  if (threadIdx.x < 2) {
    int e = top_idx[t*2 + threadIdx.x];
    int s = atomicAdd(&cursor[e], 1);
    sl[threadIdx.x] = s;
    slot_of[t*2 + threadIdx.x] = s;
  }
  __syncthreads();
  uint4 v = *(const uint4*)(xn2b + (size_t)t * DMODEL + threadIdx.x * 8);
  *(uint4*)(Xg + (size_t)sl[0] * DMODEL + threadIdx.x * 8) = v;
  *(uint4*)(Xg + (size_t)sl[1] * DMODEL + threadIdx.x * 8) = v;
}

// --- grouped MoE GEMM, bf16 MFMA, B pre-transposed bf16 Wt[e][n][k] --------
// MODE 0: silu(acc+bias) -> bf16 ; MODE 1: (acc+bias)*Hprev -> bf16 (inplace);
// MODE 2: acc+bias -> f32
template<int MODE>
__global__ __launch_bounds__(256) void tb_moe_gemm(const u16* __restrict__ Ag,
    const u16* __restrict__ Bt, const float* __restrict__ bias_b,
    const u16* __restrict__ Hprev, u16* __restrict__ out_b, float* __restrict__ out_f,
    const int* __restrict__ counts, const int* __restrict__ offs, int K, int N) {
  int e = blockIdx.z;
  int cnt = counts[e];
  if ((int)blockIdx.y * 128 >= cnt) return;
  int row0 = offs[e] + blockIdx.y * 128;
  int rend = offs[e] + cnt;
  int col0 = blockIdx.x * 128;
  const u16* Bw = Bt + (size_t)e * K * N;
  const float* bias = bias_b + (size_t)e * N;
  __shared__ __align__(16) u16 As[128*40];   // [row][k]
  __shared__ __align__(16) u16 Bs[128*40];   // [col][k]
  int tid = threadIdx.x;
  int lane = tid & 63, wave = tid >> 6;
  int wm = wave >> 1, wn = wave & 1;
  int l15 = lane & 15, l4 = lane >> 4;
  int sr = tid >> 1, skh = (tid & 1) * 16;
  f32x4 zero = {0.f, 0.f, 0.f, 0.f};
  f32x4 acc[4][4];
  #pragma unroll
  for (int i=0;i<4;++i) for (int j=0;j<4;++j) acc[i][j] = zero;
  for (int k0 = 0; k0 < K; k0 += 32) {
    { // A stage (bf16 copy, row-bounds-checked)
      uint4 v0 = make_uint4(0,0,0,0), v1 = make_uint4(0,0,0,0);
      if (row0 + sr < rend) {
        const u16* ap = Ag + (size_t)(row0 + sr) * K + k0 + skh;
        v0 = ((const uint4*)ap)[0];
        v1 = ((const uint4*)ap)[1];
      }
      *(uint4*)(As + sr*40 + skh)     = v0;
      *(uint4*)(As + sr*40 + skh + 8) = v1;
    }
    { // B stage (pre-transposed bf16 copy)
      const u16* bp = Bw + (size_t)(col0 + sr) * K + k0 + skh;
      *(uint4*)(Bs + sr*40 + skh)     = ((const uint4*)bp)[0];
      *(uint4*)(Bs + sr*40 + skh + 8) = ((const uint4*)bp)[1];
    }
    __syncthreads();
    bf16x8 af[4], bfr[4];
    #pragma unroll
    for (int mi = 0; mi < 4; ++mi)
      af[mi] = *(const bf16x8*)(As + (wm*64 + mi*16 + l15)*40 + l4*8);
    #pragma unroll
    for (int ni = 0; ni < 4; ++ni)
      bfr[ni] = *(const bf16x8*)(Bs + (wn*64 + ni*16 + l15)*40 + l4*8);
    #pragma unroll
    for (int mi = 0; mi < 4; ++mi)
      #pragma unroll
      for (int ni = 0; ni < 4; ++ni)
        acc[mi][ni] = __builtin_amdgcn_mfma_f32_16x16x32_bf16(af[mi], bfr[ni], acc[mi][ni], 0, 0, 0);
    __syncthreads();
  }
  #pragma unroll
  for (int mi = 0; mi < 4; ++mi) {
    #pragma unroll
    for (int r = 0; r < 4; ++r) {
      int row = row0 + wm*64 + mi*16 + l4*4 + r;
      if (row >= rend) continue;
      #pragma unroll
      for (int ni = 0; ni < 4; ++ni) {
        int col = col0 + wn*64 + ni*16 + l15;
        float vv = acc[mi][ni][r] + bias[col];
        size_t oi = (size_t)row * N + col;
        if (MODE == 0)      out_b[oi] = f2bf(vv / (1.f + expf(-vv)));
        else if (MODE == 1) out_b[oi] = f2bf(bf2f(Hprev[oi]) * vv);
        else                out_f[oi] = vv;
      }
    }
  }
}

__global__ __launch_bounds__(256) void tb_combine(const float* __restrict__ x1,
    const float* __restrict__ outp, const int* __restrict__ slot_of,
    const float* __restrict__ gate_w, float* __restrict__ out) {
  int t = blockIdx.x;
  int s0 = slot_of[t*2], s1 = slot_of[t*2+1];
  float g0 = gate_w[t*2], g1 = gate_w[t*2+1];
  int c = threadIdx.x * 4;
  float4 a  = *(const float4*)(x1   + (size_t)t *DMODEL + c);
  float4 p0 = *(const float4*)(outp + (size_t)s0*DMODEL + c);
  float4 p1 = *(const float4*)(outp + (size_t)s1*DMODEL + c);
  float4 o;
  o.x = a.x + g0*p0.x + g1*p1.x;
  o.y = a.y + g0*p0.y + g1*p1.y;
  o.z = a.z + g0*p0.z + g1*p1.z;
  o.w = a.w + g0*p0.w + g1*p1.w;
  *(float4*)(out + (size_t)t*DMODEL + c) = o;
}

extern "C" void kernel_launch(void* const* d_in, const int* in_sizes, int n_in,
                              void* d_out, int out_size, void* d_ws, size_t ws_size,
                              hipStream_t stream) {
  const float* x      = (const float*)d_in[0];
  const float* w_qkv  = (const float*)d_in[1];
  const float* b_qkv  = (const float*)d_in[2];
  const float* w_out  = (const float*)d_in[3];
  const float* b_out  = (const float*)d_in[4];
  const float* scale1 = (const float*)d_in[5];
  const float* scale2 = (const float*)d_in[6];
  const float* w_gate = (const float*)d_in[7];
  const float* b_gate = (const float*)d_in[8];
  const float* w1     = (const float*)d_in[9];
  const float* b1     = (const float*)d_in[10];
  const float* w2     = (const float*)d_in[11];
  const float* b2     = (const float*)d_in[12];
  const float* wp     = (const float*)d_in[13];
  const float* bp     = (const float*)d_in[14];
  float* out = (float*)d_out;

  char* ws = (char*)d_ws;
  const size_t MB = 1024 * 1024;
  // Workspace overlay (~133MB peak). MoE-phase residents:
  float* XN1  = (float*)(ws + 0*MB);    // 8MB; dead after QKV gemm
  u16*   XG   = (u16*)  (ws + 0*MB);    // 8MB  (overlay XN1)
  float* X1   = (float*)(ws + 8*MB);    // 8MB  alive till combine
  float* OUTP = (float*)(ws + 16*MB);   // 16MB [16,32)
  float* XN2F = (float*)(ws + 16*MB);   // 8MB  (overlay OUTP; dead after gating)
  u16*   XN2B = (u16*)  (ws + 32*MB);   // 4MB
  u16*   HB   = (u16*)  (ws + 36*MB);   // 32MB [36,68)
  u16*   WT   = (u16*)  (ws + 68*MB);   // 64MB [68,132) shared MoE weight region
  // Attention-phase overlays (all dead before the MoE writes land):
  float* QKV  = (float*)(ws + 36*MB);   // 24MB [36,60)  (inside HB)
  float* Qf   = (float*)(ws + 60*MB);   // 8MB  [60,68)  (inside HB)
  float* Vf   = (float*)(ws + 68*MB);   // 8MB  [68,76)  (inside WT)
  u16*   Khg  = (u16*)  (ws + 76*MB);   // 4MB
  u16*   Klg  = (u16*)  (ws + 80*MB);   // 4MB
  u16*   Vth  = (u16*)  (ws + 84*MB);   // 4MB
  u16*   Vtl  = (u16*)  (ws + 88*MB);   // 4MB
  float* Ob   = (float*)(ws + 92*MB);   // 8MB
  u16*   Wqh  = (u16*)  (ws + 100*MB);  // 6MB
  u16*   Wql  = (u16*)  (ws + 106*MB);  // 6MB
  u16*   Woh  = (u16*)  (ws + 112*MB);  // 2MB
  u16*   Wol  = (u16*)  (ws + 114*MB);  // 2MB
  char*  GT   = ws + 132*MB;
  int*   top_idx = (int*)  (GT);
  float* gate_w  = (float*)(GT + 16*1024);
  int*   slot_of = (int*)  (GT + 32*1024);
  int*   counts  = (int*)  (GT + 48*1024);
  int*   offs    = (int*)  (GT + 48*1024 + 64);
  int*   cursor  = (int*)  (GT + 48*1024 + 128);
  float* trig    = (float*)(GT + 64*1024);

  hipMemsetAsync(counts, 0, 32, stream);
  tb_trig<<<1024, 32, 0, stream>>>(trig);
  tb_wsplit<1><<<dim3(48,16,1), 256, 0, stream>>>(w_qkv, Wqh, Wql, 1024, 3072);
  tb_wsplit<1><<<dim3(16,16,1), 256, 0, stream>>>(w_out, Woh, Wol, 1024, 1024);
  tb_rms<0><<<2048, 256, 0, stream>>>(x, scale1, XN1, nullptr);
  tb_gemm_sp<0><<<dim3(24,16), 256, 0, stream>>>(XN1, Wqh, Wql, b_qkv, nullptr, QKV, 2048, 3072, 1024);
  tb_rope2<<<2048, 256, 0, stream>>>(QKV, trig, Qf, Khg, Klg, Vf);
  tb_vt<<<dim3(16,32), 256, 0, stream>>>(Vf, Vth, Vtl);
  tb_attn_mfma<<<dim3(16,32), 256, 0, stream>>>(Qf, Khg, Klg, Vth, Vtl, Ob);
  tb_gemm_sp<1><<<dim3(8,16), 256, 0, stream>>>(Ob, Woh, Wol, b_out, x, X1, 2048, 1024, 1024);
  tb_rms<1><<<2048, 256, 0, stream>>>(X1, scale2, XN2F, XN2B);
  tb_gating<<<2048, 64, 0, stream>>>(XN2F, w_gate, b_gate, top_idx, gate_w, counts);
  tb_scan<<<1, 64, 0, stream>>>(counts, offs, cursor, out + (size_t)NTOK*DMODEL);
  tb_gather<<<2048, 128, 0, stream>>>(XN2B, top_idx, cursor, slot_of, XG);
  // MoE: convert each weight tensor into the shared WT region, then GEMM.
  tb_wsplit<0><<<dim3(64,16,8), 256, 0, stream>>>(w1, WT, nullptr, 1024, 4096);
  tb_moe_gemm<0><<<dim3(32,16,8), 256, 0, stream>>>(XG, WT, b1, nullptr, HB, nullptr, counts, offs, 1024, 4096);
  tb_wsplit<0><<<dim3(64,16,8), 256, 0, stream>>>(w2, WT, nullptr, 1024, 4096);
  tb_moe_gemm<1><<<dim3(32,16,8), 256, 0, stream>>>(XG, WT, b2, HB, HB, nullptr, counts, offs, 1024, 4096);
  tb_wsplit<0><<<dim3(16,64,8), 256, 0, stream>>>(wp, WT, nullptr, 4096, 1024);
  tb_moe_gemm<2><<<dim3(8,16,8), 256, 0, stream>>>(HB, WT, bp, nullptr, nullptr, OUTP, counts, offs, 4096, 1024);
  tb_combine<<<2048, 256, 0, stream>>>(X1, OUTP, slot_of, gate_w, out);
}

// Round 4
// 691.954 us; speedup vs baseline: 3.1211x; 1.0694x over previous
//
#include <hip/hip_runtime.h>
#include <math.h>

typedef unsigned short u16;
typedef unsigned int   u32;
typedef float f32x4 __attribute__((ext_vector_type(4)));
typedef __bf16 bf16x8 __attribute__((ext_vector_type(8)));

#define T_LEN  1024
#define DMODEL 1024
#define NTOK   2048
#define NHEAD  16
#define HDIM   64
#define NEXP   8
#define FFDIM  4096

__device__ __forceinline__ u16 f2bf(float f) {          // RNE
  union { float f; u32 u; } v; v.f = f;
  u32 r = v.u + 0x7FFFu + ((v.u >> 16) & 1u);
  return (u16)(r >> 16);
}
__device__ __forceinline__ float bf2f(u16 h) {
  union { u32 u; float f; } v; v.u = ((u32)h) << 16; return v.f;
}
union b8u { uint4 u; bf16x8 b; };

// async 16B global->LDS (wave-uniform LDS base; HW adds lane*16)
__device__ __forceinline__ void g2l16(const u16* src, u16* ldsbase) {
  __builtin_amdgcn_global_load_lds(
      (const __attribute__((address_space(1))) void*)src,
      (__attribute__((address_space(3))) void*)ldsbase, 16, 0, 0);
}

// split 16 f32 -> 8 packed u32 hi + 8 packed u32 lo
__device__ __forceinline__ void split16(const float* src, u32* H, u32* L) {
  #pragma unroll
  for (int j = 0; j < 8; ++j) {
    float a = src[2*j], b = src[2*j+1];
    u16 ha = f2bf(a), hb = f2bf(b);
    u16 la = f2bf(a - bf2f(ha)), lb = f2bf(b - bf2f(hb));
    H[j] = (u32)ha | ((u32)hb << 16);
    L[j] = (u32)la | ((u32)lb << 16);
  }
}

// ---------------- RMSNorm (f64 accumulate) ---------------------------------
template<int WRITE_B>
__global__ __launch_bounds__(256) void tb_rms(const float* __restrict__ x,
    const float* __restrict__ scale, float* __restrict__ out_f, u16* __restrict__ out_b) {
  int t = blockIdx.x, tid = threadIdx.x;
  const float* xr = x + (size_t)t * DMODEL;
  float4 v = *(const float4*)(xr + tid * 4);
  double ss = (double)v.x*v.x + (double)v.y*v.y + (double)v.z*v.z + (double)v.w*v.w;
  #pragma unroll
  for (int off = 32; off; off >>= 1) ss += __shfl_xor(ss, off);
  __shared__ double red[4];
  if ((tid & 63) == 0) red[tid >> 6] = ss;
  __syncthreads();
  double denom = sqrt((red[0]+red[1]+red[2]+red[3]) / (double)DMODEL) + 1e-5;
  float4 sc = *(const float4*)(scale + tid * 4);
  float y0 = (float)((double)v.x / denom * (double)sc.x);
  float y1 = (float)((double)v.y / denom * (double)sc.y);
  float y2 = (float)((double)v.z / denom * (double)sc.z);
  float y3 = (float)((double)v.w / denom * (double)sc.w);
  *(float4*)(out_f + (size_t)t*DMODEL + tid*4) = make_float4(y0,y1,y2,y3);
  if (WRITE_B) {
    u16* ob = out_b + (size_t)t*DMODEL + tid*4;
    ob[0]=f2bf(y0); ob[1]=f2bf(y1); ob[2]=f2bf(y2); ob[3]=f2bf(y3);
  }
}

// ------- weight pre-split+transpose: W[k][n] f32 -> Wt[n][k] bf16 (hi[,lo]) -
template<int HILO>
__global__ __launch_bounds__(256) void tb_wsplit(const float* __restrict__ W,
    u16* __restrict__ Wh, u16* __restrict__ Wl, int K, int N) {
  __shared__ float Tf[64*68];
  size_t eo = (size_t)blockIdx.z * (size_t)K * N;
  const float* Wb = W + eo;
  int n0 = blockIdx.x*64, k0 = blockIdx.y*64;
  int tid = threadIdx.x;
  int r = tid >> 2, c = tid & 3;
  const float* wp = Wb + (size_t)(k0+r)*N + n0 + c*16;
  float vv[16];
  *(float4*)&vv[0]  = ((const float4*)wp)[0];
  *(float4*)&vv[4]  = ((const float4*)wp)[1];
  *(float4*)&vv[8]  = ((const float4*)wp)[2];
  *(float4*)&vv[12] = ((const float4*)wp)[3];
  #pragma unroll
  for (int j = 0; j < 16; ++j) Tf[(c*16+j)*68 + r] = vv[j];
  __syncthreads();
  int n = tid >> 2, kc = tid & 3;
  float tv[16];
  #pragma unroll
  for (int j = 0; j < 16; ++j) tv[j] = Tf[n*68 + kc*16 + j];
  u32 H[8], L[8];
  split16(tv, H, L);
  u16* oh = Wh + eo + (size_t)(n0+n)*K + k0 + kc*16;
  *(uint4*)oh       = make_uint4(H[0],H[1],H[2],H[3]);
  *(uint4*)(oh + 8) = make_uint4(H[4],H[5],H[6],H[7]);
  if (HILO) {
    u16* ol = Wl + eo + (size_t)(n0+n)*K + k0 + kc*16;
    *(uint4*)ol       = make_uint4(L[0],L[1],L[2],L[3]);
    *(uint4*)(ol + 8) = make_uint4(L[4],L[5],L[6],L[7]);
  }
}

// ---------------- split-bf16 MFMA GEMM: C = A(f32) * Wt + bias [+resid] ----
// A reg-staged (needs on-the-fly hi/lo split); B via global_load_lds (linear
// LDS + chunk-XOR swizzle on source and read — rule #21 both-sides).
template<int RESID>
__global__ __launch_bounds__(256) void tb_gemm_sp(const float* __restrict__ A,
    const u16* __restrict__ Bhg, const u16* __restrict__ Blg,
    const float* __restrict__ bias, const float* __restrict__ resid,
    float* __restrict__ C, int M, int N, int K) {
  __shared__ __align__(16) u16 Ah[128*40], Al[128*40];   // padded (ds_write path)
  __shared__ __align__(16) u16 Bh[128*32], Bl[128*32];   // linear (gload_lds)
  int tid = threadIdx.x;
  int row0 = blockIdx.y * 128, col0 = blockIdx.x * 128;
  int lane = tid & 63, wave = tid >> 6;
  int wm = wave >> 1, wn = wave & 1;
  int l15 = lane & 15, l4 = lane >> 4;
  int sw = (l15 >> 1) & 3;
  int sr = tid >> 1, skh = (tid & 1) * 16;
  f32x4 zero = {0.f,0.f,0.f,0.f};
  f32x4 acc[4][4];
  #pragma unroll
  for (int i=0;i<4;++i) for (int j=0;j<4;++j) acc[i][j] = zero;
  for (int k0 = 0; k0 < K; k0 += 32) {
    // B stage first (async, no VGPR round-trip)
    #pragma unroll
    for (int j = 0; j < 2; ++j) {
      int ci = ((wave*2 + j) << 6) + lane;      // 16B-chunk index in tile
      int row = ci >> 2, ch = ci & 3;
      int kof = k0 + ((ch ^ ((row >> 1) & 3)) << 3);
      g2l16(Bhg + (size_t)(col0 + row) * K + kof, Bh + ((wave*2 + j) << 9));
      g2l16(Blg + (size_t)(col0 + row) * K + kof, Bl + ((wave*2 + j) << 9));
    }
    { // A stage: f32 -> hi/lo bf16 (reg path)
      const float* ap = A + (size_t)(row0+sr)*K + k0 + skh;
      float vv[16];
      *(float4*)&vv[0]  = ((const float4*)ap)[0];
      *(float4*)&vv[4]  = ((const float4*)ap)[1];
      *(float4*)&vv[8]  = ((const float4*)ap)[2];
      *(float4*)&vv[12] = ((const float4*)ap)[3];
      u32 H[8], L[8];
      split16(vv, H, L);
      *(uint4*)(Ah + sr*40 + skh)     = make_uint4(H[0],H[1],H[2],H[3]);
      *(uint4*)(Ah + sr*40 + skh + 8) = make_uint4(H[4],H[5],H[6],H[7]);
      *(uint4*)(Al + sr*40 + skh)     = make_uint4(L[0],L[1],L[2],L[3]);
      *(uint4*)(Al + sr*40 + skh + 8) = make_uint4(L[4],L[5],L[6],L[7]);
    }
    __syncthreads();
    bf16x8 ah[4], al_[4], bh_[4], bl_[4];
    #pragma unroll
    for (int mi = 0; mi < 4; ++mi) {
      ah[mi]  = *(const bf16x8*)(Ah + (wm*64 + mi*16 + l15)*40 + l4*8);
      al_[mi] = *(const bf16x8*)(Al + (wm*64 + mi*16 + l15)*40 + l4*8);
    }
    #pragma unroll
    for (int ni = 0; ni < 4; ++ni) {
      int ro = (wn*64 + ni*16 + l15) << 5;
      bh_[ni] = *(const bf16x8*)(Bh + ro + ((l4 ^ sw) << 3));
      bl_[ni] = *(const bf16x8*)(Bl + ro + ((l4 ^ sw) << 3));
    }
    #pragma unroll
    for (int mi = 0; mi < 4; ++mi)
      #pragma unroll
      for (int ni = 0; ni < 4; ++ni) {
        acc[mi][ni] = __builtin_amdgcn_mfma_f32_16x16x32_bf16(ah[mi], bh_[ni], acc[mi][ni], 0,0,0);
        acc[mi][ni] = __builtin_amdgcn_mfma_f32_16x16x32_bf16(ah[mi], bl_[ni], acc[mi][ni], 0,0,0);
        acc[mi][ni] = __builtin_amdgcn_mfma_f32_16x16x32_bf16(al_[mi], bh_[ni], acc[mi][ni], 0,0,0);
      }
    __syncthreads();
  }
  #pragma unroll
  for (int mi = 0; mi < 4; ++mi)
    #pragma unroll
    for (int r = 0; r < 4; ++r) {
      int row = row0 + wm*64 + mi*16 + l4*4 + r;
      #pragma unroll
      for (int ni = 0; ni < 4; ++ni) {
        int col = col0 + wn*64 + ni*16 + l15;
        float vv = acc[mi][ni][r] + bias[col];
        if (RESID) vv += resid[(size_t)row*N + col];
        C[(size_t)row*N + col] = vv;
      }
    }
}

// ---------------- RoPE trig table (f64) ------------------------------------
__global__ void tb_trig(float* __restrict__ tab) {
  int t = blockIdx.x, d = threadIdx.x;
  double theta = pow(10000.0, -(double)d / 32.0);
  double ang = (double)t * theta;
  tab[(t*32 + d)*2 + 0] = (float)cos(ang);
  tab[(t*32 + d)*2 + 1] = (float)sin(ang);
}

// ---------------- qkv -> Q f32, K bf16 hi/lo (all [bh][t][d]), V f32 -------
__global__ __launch_bounds__(256) void tb_rope2(const float* __restrict__ qkv,
    const float* __restrict__ tab, float* __restrict__ Qf, u16* __restrict__ Khg,
    u16* __restrict__ Klg, float* __restrict__ Vf) {
  int n = blockIdx.x;
  int b = n >> 10, t = n & 1023;
  const float* src = qkv + (size_t)n * 3072;
  for (int idx = threadIdx.x; idx < 512; idx += 256) {
    int h = idx >> 5, d = idx & 31;
    float ca = tab[(t*32+d)*2], sa = tab[(t*32+d)*2+1];
    size_t base = ((size_t)(b*NHEAD + h) * T_LEN + t) * HDIM;
    { float x1 = src[h*64 + d], x2 = src[h*64 + d + 32];
      Qf[base + d]      = x1*ca - x2*sa;
      Qf[base + d + 32] = x1*sa + x2*ca; }
    { float x1 = src[1024 + h*64 + d], x2 = src[1024 + h*64 + d + 32];
      float k1 = x1*ca - x2*sa, k2 = x1*sa + x2*ca;
      u16 h1 = f2bf(k1), h2 = f2bf(k2);
      Khg[base + d] = h1;      Khg[base + d + 32] = h2;
      Klg[base + d] = f2bf(k1 - bf2f(h1));
      Klg[base + d + 32] = f2bf(k2 - bf2f(h2)); }
  }
  for (int c = threadIdx.x; c < 1024; c += 256) {
    int h = c >> 6, d = c & 63;
    Vf[((size_t)(b*NHEAD + h) * T_LEN + t) * HDIM + d] = src[2048 + c];
  }
}

// ---------------- V transpose+split: [bh][t][d] f32 -> [bh][d][t] bf16 -----
__global__ __launch_bounds__(256) void tb_vt(const float* __restrict__ Vf,
    u16* __restrict__ Vh, u16* __restrict__ Vl) {
  __shared__ float Tf[64*68];
  int t0 = blockIdx.x * 64, bh = blockIdx.y;
  const float* Vb = Vf + (size_t)bh * (T_LEN*HDIM);
  int tid = threadIdx.x, r = tid >> 2, c = tid & 3;
  const float* vp = Vb + (size_t)(t0+r)*HDIM + c*16;
  float vv[16];
  *(float4*)&vv[0]  = ((const float4*)vp)[0];
  *(float4*)&vv[4]  = ((const float4*)vp)[1];
  *(float4*)&vv[8]  = ((const float4*)vp)[2];
  *(float4*)&vv[12] = ((const float4*)vp)[3];
  #pragma unroll
  for (int j = 0; j < 16; ++j) Tf[(c*16+j)*68 + r] = vv[j];
  __syncthreads();
  int d = tid >> 2, tc = tid & 3;
  float tv[16];
  #pragma unroll
  for (int j = 0; j < 16; ++j) tv[j] = Tf[d*68 + tc*16 + j];
  u32 H[8], L[8];
  split16(tv, H, L);
  u16* oh = Vh + (size_t)bh*(HDIM*T_LEN) + (size_t)d*T_LEN + t0 + tc*16;
  u16* ol = Vl + (size_t)bh*(HDIM*T_LEN) + (size_t)d*T_LEN + t0 + tc*16;
  *(uint4*)oh       = make_uint4(H[0],H[1],H[2],H[3]);
  *(uint4*)(oh + 8) = make_uint4(H[4],H[5],H[6],H[7]);
  *(uint4*)ol       = make_uint4(L[0],L[1],L[2],L[3]);
  *(uint4*)(ol + 8) = make_uint4(L[4],L[5],L[6],L[7]);
}

// ---------------- MFMA flash attention (split-bf16, fp32 accuracy) ---------
__global__ __launch_bounds__(256) void tb_attn_mfma(const float* __restrict__ Qf,
    const u16* __restrict__ Khg, const u16* __restrict__ Klg,
    const u16* __restrict__ Vhg, const u16* __restrict__ Vlg,
    float* __restrict__ Og) {
  __shared__ __align__(16) u16 Kh[64*72], Kl[64*72];
  __shared__ __align__(16) u16 Vh[64*72], Vl[64*72];
  __shared__ __align__(16) u16 Ph[64*72], Pl[64*72];
  int qt = blockIdx.x, bh = blockIdx.y;
  int tid = threadIdx.x, lane = tid & 63, w = tid >> 6;
  int l15 = lane & 15, l4 = lane >> 4;
  int b = bh >> 4, h = bh & 15;
  const float* Qb = Qf + (size_t)bh * (T_LEN*HDIM);
  const u16* Khb = Khg + (size_t)bh * (T_LEN*HDIM);
  const u16* Klb = Klg + (size_t)bh * (T_LEN*HDIM);
  const u16* Vhb = Vhg + (size_t)bh * (HDIM*T_LEN);
  const u16* Vlb = Vlg + (size_t)bh * (HDIM*T_LEN);
  int q0 = qt * 64;
  int qrow = q0 + w*16 + l15;
  bf16x8 qh[2], ql[2];
  #pragma unroll
  for (int ks = 0; ks < 2; ++ks) {
    const float* qp = Qb + (size_t)qrow*HDIM + ks*32 + l4*8;
    float vv[8];
    *(float4*)&vv[0] = ((const float4*)qp)[0];
    *(float4*)&vv[4] = ((const float4*)qp)[1];
    u32 H[4], L[4];
    #pragma unroll
    for (int j = 0; j < 4; ++j) {
      float a = vv[2*j], bb = vv[2*j+1];
      u16 ha = f2bf(a), hb = f2bf(bb);
      u16 la = f2bf(a - bf2f(ha)), lb = f2bf(bb - bf2f(hb));
      H[j] = (u32)ha | ((u32)hb << 16);
      L[j] = (u32)la | ((u32)lb << 16);
    }
    b8u th, tl;
    th.u = make_uint4(H[0],H[1],H[2],H[3]);
    tl.u = make_uint4(L[0],L[1],L[2],L[3]);
    qh[ks] = th.b; ql[ks] = tl.b;
  }
  int qg[4];
  #pragma unroll
  for (int r = 0; r < 4; ++r) qg[r] = q0 + w*16 + l4*4 + r;
  float mrow[4], lrow[4];
  f32x4 oacc[4];
  f32x4 zero = {0.f,0.f,0.f,0.f};
  #pragma unroll
  for (int r = 0; r < 4; ++r) { mrow[r] = -1e30f; lrow[r] = 0.f; }
  #pragma unroll
  for (int d = 0; d < 4; ++d) oacc[d] = zero;

  int sr = tid >> 2, sc = tid & 3;
  for (int kt = 0; kt <= qt; ++kt) {
    int k0 = kt * 64;
    __syncthreads();
    {
      const u16* kp = Khb + (size_t)(k0+sr)*HDIM + sc*16;
      *(uint4*)(Kh + sr*72 + sc*16)     = ((const uint4*)kp)[0];
      *(uint4*)(Kh + sr*72 + sc*16 + 8) = ((const uint4*)kp)[1];
      const u16* kl2 = Klb + (size_t)(k0+sr)*HDIM + sc*16;
      *(uint4*)(Kl + sr*72 + sc*16)     = ((const uint4*)kl2)[0];
      *(uint4*)(Kl + sr*72 + sc*16 + 8) = ((const uint4*)kl2)[1];
      const u16* vp = Vhb + (size_t)sr*T_LEN + k0 + sc*16;
      *(uint4*)(Vh + sr*72 + sc*16)     = ((const uint4*)vp)[0];
      *(uint4*)(Vh + sr*72 + sc*16 + 8) = ((const uint4*)vp)[1];
      const u16* vl2 = Vlb + (size_t)sr*T_LEN + k0 + sc*16;
      *(uint4*)(Vl + sr*72 + sc*16)     = ((const uint4*)vl2)[0];
      *(uint4*)(Vl + sr*72 + sc*16 + 8) = ((const uint4*)vl2)[1];
    }
    __syncthreads();
    f32x4 sacc[4];
    #pragma unroll
    for (int ni = 0; ni < 4; ++ni) {
      sacc[ni] = zero;
      #pragma unroll
      for (int ks = 0; ks < 2; ++ks) {
        bf16x8 kh_ = *(const bf16x8*)(Kh + (ni*16 + l15)*72 + ks*32 + l4*8);
        bf16x8 kl_ = *(const bf16x8*)(Kl + (ni*16 + l15)*72 + ks*32 + l4*8);
        sacc[ni] = __builtin_amdgcn_mfma_f32_16x16x32_bf16(qh[ks], kh_, sacc[ni], 0,0,0);
        sacc[ni] = __builtin_amdgcn_mfma_f32_16x16x32_bf16(qh[ks], kl_, sacc[ni], 0,0,0);
        sacc[ni] = __builtin_amdgcn_mfma_f32_16x16x32_bf16(ql[ks], kh_, sacc[ni], 0,0,0);
      }
    }
    bool diag = (kt == qt);
    float sv[4][4];
    #pragma unroll
    for (int ni = 0; ni < 4; ++ni)
      #pragma unroll
      for (int r = 0; r < 4; ++r) {
        float s = sacc[ni][r] * 0.125f;
        if (diag && (k0 + ni*16 + l15 > qg[r])) s = -1e30f;
        sv[ni][r] = s;
      }
    float mt[4];
    #pragma unroll
    for (int r = 0; r < 4; ++r)
      mt[r] = fmaxf(fmaxf(sv[0][r], sv[1][r]), fmaxf(sv[2][r], sv[3][r]));
    #pragma unroll
    for (int off = 1; off < 16; off <<= 1)
      #pragma unroll
      for (int r = 0; r < 4; ++r) mt[r] = fmaxf(mt[r], __shfl_xor(mt[r], off));
    float al[4];
    #pragma unroll
    for (int r = 0; r < 4; ++r) {
      float mn = fmaxf(mrow[r], mt[r]);
      al[r] = expf(mrow[r] - mn);
      mrow[r] = mn;
    }
    float ls[4] = {0.f,0.f,0.f,0.f};
    #pragma unroll
    for (int ni = 0; ni < 4; ++ni)
      #pragma unroll
      for (int r = 0; r < 4; ++r) {
        float p = expf(sv[ni][r] - mrow[r]);
        u16 ph2 = f2bf(p);
        int qrl = w*16 + l4*4 + r;
        Ph[qrl*72 + ni*16 + l15] = ph2;
        Pl[qrl*72 + ni*16 + l15] = f2bf(p - bf2f(ph2));
        ls[r] += p;
      }
    #pragma unroll
    for (int off = 1; off < 16; off <<= 1)
      #pragma unroll
      for (int r = 0; r < 4; ++r) ls[r] += __shfl_xor(ls[r], off);
    #pragma unroll
    for (int r = 0; r < 4; ++r) lrow[r] = lrow[r]*al[r] + ls[r];
    #pragma unroll
    for (int d = 0; d < 4; ++d)
      #pragma unroll
      for (int r = 0; r < 4; ++r) oacc[d][r] *= al[r];
    bf16x8 ph_[2], pl_[2];
    #pragma unroll
    for (int ks = 0; ks < 2; ++ks) {
      ph_[ks] = *(const bf16x8*)(Ph + (w*16 + l15)*72 + ks*32 + l4*8);
      pl_[ks] = *(const bf16x8*)(Pl + (w*16 + l15)*72 + ks*32 + l4*8);
    }
    #pragma unroll
    for (int dblk = 0; dblk < 4; ++dblk)
      #pragma unroll
      for (int ks = 0; ks < 2; ++ks) {
        bf16x8 vh_ = *(const bf16x8*)(Vh + (dblk*16 + l15)*72 + ks*32 + l4*8);
        bf16x8 vl_ = *(const bf16x8*)(Vl + (dblk*16 + l15)*72 + ks*32 + l4*8);
        oacc[dblk] = __builtin_amdgcn_mfma_f32_16x16x32_bf16(ph_[ks], vh_, oacc[dblk], 0,0,0);
        oacc[dblk] = __builtin_amdgcn_mfma_f32_16x16x32_bf16(ph_[ks], vl_, oacc[dblk], 0,0,0);
        oacc[dblk] = __builtin_amdgcn_mfma_f32_16x16x32_bf16(pl_[ks], vh_, oacc[dblk], 0,0,0);
      }
  }
  #pragma unroll
  for (int dblk = 0; dblk < 4; ++dblk)
    #pragma unroll
    for (int r = 0; r < 4; ++r) {
      int q = qg[r];
      int d = dblk*16 + l15;
      Og[((size_t)b * T_LEN + q) * DMODEL + h * HDIM + d] = oacc[dblk][r] / lrow[r];
    }
}

// ---------------- router: f64 logits, top-2 --------------------------------
__global__ __launch_bounds__(64) void tb_gating(const float* __restrict__ xn2,
    const float* __restrict__ wg, const float* __restrict__ bg,
    int* __restrict__ top_idx, float* __restrict__ gate_w, int* __restrict__ counts) {
  int t = blockIdx.x, lane = threadIdx.x;
  const float* xr = xn2 + (size_t)t * DMODEL;
  double part[8];
  #pragma unroll
  for (int e = 0; e < 8; ++e) part[e] = 0.0;
  for (int i = lane; i < DMODEL; i += 64) {
    double xv = (double)xr[i];
    const float* wr = wg + (size_t)i * 8;
    #pragma unroll
    for (int e = 0; e < 8; ++e) part[e] += xv * (double)wr[e];
  }
  #pragma unroll
  for (int e = 0; e < 8; ++e)
    for (int off = 32; off; off >>= 1) part[e] += __shfl_xor(part[e], off);
  if (lane == 0) {
    double lg[8];
    for (int e = 0; e < 8; ++e) lg[e] = part[e] + (double)bg[e];
    int i1 = 0;
    for (int e = 1; e < 8; ++e) if (lg[e] > lg[i1]) i1 = e;
    int i2 = (i1 == 0) ? 1 : 0;
    for (int e = 0; e < 8; ++e) if (e != i1 && lg[e] > lg[i2]) i2 = e;
    double e2 = exp(lg[i2] - lg[i1]);
    double den = 1.0 + e2;
    top_idx[t*2] = i1; top_idx[t*2+1] = i2;
    gate_w[t*2] = (float)(1.0/den); gate_w[t*2+1] = (float)(e2/den);
    atomicAdd(&counts[i1], 1); atomicAdd(&counts[i2], 1);
  }
}

__global__ void tb_scan(const int* __restrict__ counts, int* __restrict__ offs,
    int* __restrict__ cursor, float* __restrict__ aux_out) {
  if (threadIdx.x == 0) {
    int off = 0; float aux = 0.f;
    for (int e = 0; e < 8; ++e) {
      offs[e] = off; cursor[e] = off; off += counts[e];
      float fr = (float)counts[e] / 4096.0f - 0.125f;
      aux += fr * fr;
    }
    aux_out[0] = aux;
  }
}

__global__ __launch_bounds__(128) void tb_gather(const u16* __restrict__ xn2b,
    const int* __restrict__ top_idx, int* __restrict__ cursor,
    int* __restrict__ slot_of, u16* __restrict__ Xg) {
  int t = blockIdx.x;
  __shared__ int sl[2];
  if (threadIdx.x < 2) {
    int e = top_idx[t*2 + threadIdx.x];
    int s = atomicAdd(&cursor[e], 1);
    sl[threadIdx.x] = s;
    slot_of[t*2 + threadIdx.x] = s;
  }
  __syncthreads();
  uint4 v = *(const uint4*)(xn2b + (size_t)t * DMODEL + threadIdx.x * 8);
  *(uint4*)(Xg + (size_t)sl[0] * DMODEL + threadIdx.x * 8) = v;
  *(uint4*)(Xg + (size_t)sl[1] * DMODEL + threadIdx.x * 8) = v;
}

// --- grouped MoE GEMM, bf16 MFMA, gload_lds staging, chunk-XOR swizzle -----
// MODE 0: silu(acc+bias) -> bf16 ; MODE 1: (acc+bias)*Hprev -> bf16 (inplace);
// MODE 2: acc+bias -> f32
template<int MODE>
__global__ __launch_bounds__(256) void tb_moe_gemm(const u16* __restrict__ Ag,
    const u16* __restrict__ Bt, const float* __restrict__ bias_b,
    const u16* __restrict__ Hprev, u16* __restrict__ out_b, float* __restrict__ out_f,
    const int* __restrict__ counts, const int* __restrict__ offs, int K, int N) {
  int e = blockIdx.z;
  int cnt = counts[e];
  if ((int)blockIdx.y * 128 >= cnt) return;
  int row0 = offs[e] + blockIdx.y * 128;
  int rend = offs[e] + cnt;
  int col0 = blockIdx.x * 128;
  const u16* Bw = Bt + (size_t)e * K * N;
  const float* bias = bias_b + (size_t)e * N;
  __shared__ __align__(16) u16 As[128*32];   // linear [row][k], 8KB
  __shared__ __align__(16) u16 Bs[128*32];   // linear [col][k], 8KB
  int tid = threadIdx.x;
  int lane = tid & 63, wave = tid >> 6;
  int wm = wave >> 1, wn = wave & 1;
  int l15 = lane & 15, l4 = lane >> 4;
  int sw = (l15 >> 1) & 3;
  // per-lane staging geometry (2 issues per wave per tile)
  int ci0 = ((wave*2 + 0) << 6) + lane, ci1 = ((wave*2 + 1) << 6) + lane;
  int ar0 = ci0 >> 2, ac0 = ((ci0 & 3) ^ ((ar0 >> 1) & 3)) << 3;
  int ar1 = ci1 >> 2, ac1 = ((ci1 & 3) ^ ((ar1 >> 1) & 3)) << 3;
  int ga0 = row0 + ar0 < rend ? row0 + ar0 : rend - 1;
  int ga1 = row0 + ar1 < rend ? row0 + ar1 : rend - 1;
  f32x4 zero = {0.f, 0.f, 0.f, 0.f};
  f32x4 acc[4][4];
  #pragma unroll
  for (int i=0;i<4;++i) for (int j=0;j<4;++j) acc[i][j] = zero;
  for (int k0 = 0; k0 < K; k0 += 32) {
    g2l16(Ag + (size_t)ga0 * K + k0 + ac0,         As + ((wave*2 + 0) << 9));
    g2l16(Ag + (size_t)ga1 * K + k0 + ac1,         As + ((wave*2 + 1) << 9));
    g2l16(Bw + (size_t)(col0 + ar0) * K + k0 + ac0, Bs + ((wave*2 + 0) << 9));
    g2l16(Bw + (size_t)(col0 + ar1) * K + k0 + ac1, Bs + ((wave*2 + 1) << 9));
    __syncthreads();
    bf16x8 af[4], bfr[4];
    #pragma unroll
    for (int mi = 0; mi < 4; ++mi)
      af[mi] = *(const bf16x8*)(As + ((wm*64 + mi*16 + l15) << 5) + ((l4 ^ sw) << 3));
    #pragma unroll
    for (int ni = 0; ni < 4; ++ni)
      bfr[ni] = *(const bf16x8*)(Bs + ((wn*64 + ni*16 + l15) << 5) + ((l4 ^ sw) << 3));
    #pragma unroll
    for (int mi = 0; mi < 4; ++mi)
      #pragma unroll
      for (int ni = 0; ni < 4; ++ni)
        acc[mi][ni] = __builtin_amdgcn_mfma_f32_16x16x32_bf16(af[mi], bfr[ni], acc[mi][ni], 0, 0, 0);
    __syncthreads();
  }
  #pragma unroll
  for (int mi = 0; mi < 4; ++mi) {
    #pragma unroll
    for (int r = 0; r < 4; ++r) {
      int row = row0 + wm*64 + mi*16 + l4*4 + r;
      if (row >= rend) continue;
      #pragma unroll
      for (int ni = 0; ni < 4; ++ni) {
        int col = col0 + wn*64 + ni*16 + l15;
        float vv = acc[mi][ni][r] + bias[col];
        size_t oi = (size_t)row * N + col;
        if (MODE == 0)      out_b[oi] = f2bf(vv / (1.f + expf(-vv)));
        else if (MODE == 1) out_b[oi] = f2bf(bf2f(Hprev[oi]) * vv);
        else                out_f[oi] = vv;
      }
    }
  }
}

__global__ __launch_bounds__(256) void tb_combine(const float* __restrict__ x1,
    const float* __restrict__ outp, const int* __restrict__ slot_of,
    const float* __restrict__ gate_w, float* __restrict__ out) {
  int t = blockIdx.x;
  int s0 = slot_of[t*2], s1 = slot_of[t*2+1];
  float g0 = gate_w[t*2], g1 = gate_w[t*2+1];
  int c = threadIdx.x * 4;
  float4 a  = *(const float4*)(x1   + (size_t)t *DMODEL + c);
  float4 p0 = *(const float4*)(outp + (size_t)s0*DMODEL + c);
  float4 p1 = *(const float4*)(outp + (size_t)s1*DMODEL + c);
  float4 o;
  o.x = a.x + g0*p0.x + g1*p1.x;
  o.y = a.y + g0*p0.y + g1*p1.y;
  o.z = a.z + g0*p0.z + g1*p1.z;
  o.w = a.w + g0*p0.w + g1*p1.w;
  *(float4*)(out + (size_t)t*DMODEL + c) = o;
}

extern "C" void kernel_launch(void* const* d_in, const int* in_sizes, int n_in,
                              void* d_out, int out_size, void* d_ws, size_t ws_size,
                              hipStream_t stream) {
  const float* x      = (const float*)d_in[0];
  const float* w_qkv  = (const float*)d_in[1];
  const float* b_qkv  = (const float*)d_in[2];
  const float* w_out  = (const float*)d_in[3];
  const float* b_out  = (const float*)d_in[4];
  const float* scale1 = (const float*)d_in[5];
  const float* scale2 = (const float*)d_in[6];
  const float* w_gate = (const float*)d_in[7];
  const float* b_gate = (const float*)d_in[8];
  const float* w1     = (const float*)d_in[9];
  const float* b1     = (const float*)d_in[10];
  const float* w2     = (const float*)d_in[11];
  const float* b2     = (const float*)d_in[12];
  const float* wp     = (const float*)d_in[13];
  const float* bp     = (const float*)d_in[14];
  float* out = (float*)d_out;

  char* ws = (char*)d_ws;
  const size_t MB = 1024 * 1024;
  // Workspace overlay (~133MB peak). MoE-phase residents:
  float* XN1  = (float*)(ws + 0*MB);    // 8MB; dead after QKV gemm
  u16*   XG   = (u16*)  (ws + 0*MB);    // 8MB  (overlay XN1)
  float* X1   = (float*)(ws + 8*MB);    // 8MB  alive till combine
  float* OUTP = (float*)(ws + 16*MB);   // 16MB [16,32)
  float* XN2F = (float*)(ws + 16*MB);   // 8MB  (overlay OUTP; dead after gating)
  u16*   XN2B = (u16*)  (ws + 32*MB);   // 4MB
  u16*   HB   = (u16*)  (ws + 36*MB);   // 32MB [36,68)
  u16*   WT   = (u16*)  (ws + 68*MB);   // 64MB [68,132) shared MoE weight region
  // Attention-phase overlays (all dead before the MoE writes land):
  float* QKV  = (float*)(ws + 36*MB);   // 24MB [36,60)  (inside HB)
  float* Qf   = (float*)(ws + 60*MB);   // 8MB  [60,68)  (inside HB)
  float* Vf   = (float*)(ws + 68*MB);   // 8MB  [68,76)  (inside WT)
  u16*   Khg  = (u16*)  (ws + 76*MB);   // 4MB
  u16*   Klg  = (u16*)  (ws + 80*MB);   // 4MB
  u16*   Vth  = (u16*)  (ws + 84*MB);   // 4MB
  u16*   Vtl  = (u16*)  (ws + 88*MB);   // 4MB
  float* Ob   = (float*)(ws + 92*MB);   // 8MB
  u16*   Wqh  = (u16*)  (ws + 100*MB);  // 6MB
  u16*   Wql  = (u16*)  (ws + 106*MB);  // 6MB
  u16*   Woh  = (u16*)  (ws + 112*MB);  // 2MB
  u16*   Wol  = (u16*)  (ws + 114*MB);  // 2MB
  char*  GT   = ws + 132*MB;
  int*   top_idx = (int*)  (GT);
  float* gate_w  = (float*)(GT + 16*1024);
  int*   slot_of = (int*)  (GT + 32*1024);
  int*   counts  = (int*)  (GT + 48*1024);
  int*   offs    = (int*)  (GT + 48*1024 + 64);
  int*   cursor  = (int*)  (GT + 48*1024 + 128);
  float* trig    = (float*)(GT + 64*1024);

  hipMemsetAsync(counts, 0, 32, stream);
  tb_trig<<<1024, 32, 0, stream>>>(trig);
  tb_wsplit<1><<<dim3(48,16,1), 256, 0, stream>>>(w_qkv, Wqh, Wql, 1024, 3072);
  tb_wsplit<1><<<dim3(16,16,1), 256, 0, stream>>>(w_out, Woh, Wol, 1024, 1024);
  tb_rms<0><<<2048, 256, 0, stream>>>(x, scale1, XN1, nullptr);
  tb_gemm_sp<0><<<dim3(24,16), 256, 0, stream>>>(XN1, Wqh, Wql, b_qkv, nullptr, QKV, 2048, 3072, 1024);
  tb_rope2<<<2048, 256, 0, stream>>>(QKV, trig, Qf, Khg, Klg, Vf);
  tb_vt<<<dim3(16,32), 256, 0, stream>>>(Vf, Vth, Vtl);
  tb_attn_mfma<<<dim3(16,32), 256, 0, stream>>>(Qf, Khg, Klg, Vth, Vtl, Ob);
  tb_gemm_sp<1><<<dim3(8,16), 256, 0, stream>>>(Ob, Woh, Wol, b_out, x, X1, 2048, 1024, 1024);
  tb_rms<1><<<2048, 256, 0, stream>>>(X1, scale2, XN2F, XN2B);
  tb_gating<<<2048, 64, 0, stream>>>(XN2F, w_gate, b_gate, top_idx, gate_w, counts);
  tb_scan<<<1, 64, 0, stream>>>(counts, offs, cursor, out + (size_t)NTOK*DMODEL);
  tb_gather<<<2048, 128, 0, stream>>>(XN2B, top_idx, cursor, slot_of, XG);
  // MoE: convert each weight tensor into the shared WT region, then GEMM.
  tb_wsplit<0><<<dim3(64,16,8), 256, 0, stream>>>(w1, WT, nullptr, 1024, 4096);
  tb_moe_gemm<0><<<dim3(32,16,8), 256, 0, stream>>>(XG, WT, b1, nullptr, HB, nullptr, counts, offs, 1024, 4096);
  tb_wsplit<0><<<dim3(64,16,8), 256, 0, stream>>>(w2, WT, nullptr, 1024, 4096);
  tb_moe_gemm<1><<<dim3(32,16,8), 256, 0, stream>>>(XG, WT, b2, HB, HB, nullptr, counts, offs, 1024, 4096);
  tb_wsplit<0><<<dim3(16,64,8), 256, 0, stream>>>(wp, WT, nullptr, 4096, 1024);
  tb_moe_gemm<2><<<dim3(8,16,8), 256, 0, stream>>>(HB, WT, bp, nullptr, nullptr, OUTP, counts, offs, 4096, 1024);
  tb_combine<<<2048, 256, 0, stream>>>(X1, OUTP, slot_of, gate_w, out);
}